// Round 3
// baseline (1620.797 us; speedup 1.0000x reference)
//
#include <hip/hip_runtime.h>
#include <math.h>

#define B_ 4
#define T_ 1024
#define DIM_ 512
#define H_ 8
#define DH_ 64
#define FF_ 2048
#define KW 31

#define BM 64
#define BN 128
#define BK 16

__device__ __forceinline__ float geluf(float x) {
  return 0.5f * x * (1.f + erff(x * 0.70710678118654752f));
}
__device__ __forceinline__ float sigmoidf_(float x) {
  return 1.f / (1.f + expf(-x));
}

// ---------------- transpose (B,R,C) -> (B,C,R) ----------------
__global__ __launch_bounds__(256)
void transpose_k(const float* __restrict__ in, float* __restrict__ out, int R, int C) {
  __shared__ float tile[32][33];
  int b = blockIdx.z;
  const float* ib = in + (size_t)b * R * C;
  float* ob = out + (size_t)b * R * C;
  int c0 = blockIdx.x * 32, r0 = blockIdx.y * 32;
  int tx = threadIdx.x, ty = threadIdx.y;
  #pragma unroll
  for (int i = ty; i < 32; i += 8)
    tile[i][tx] = ib[(size_t)(r0 + i) * C + c0 + tx];
  __syncthreads();
  #pragma unroll
  for (int i = ty; i < 32; i += 8)
    ob[(size_t)(c0 + i) * R + r0 + tx] = tile[tx][i];
}

// ---------------- generic fp32 tiled GEMM ----------------
// C[m,n] = (HASRES? res[m,n] + resScale * : ) act( sum_k A[m,k]*W(k,n) + bias[n] )
// W(k,n) = TRANSB ? W[n*K+k] : W[k*N+n].  ACT: 0 none, 1 exact gelu.
// Inner loop reads LDS via float4 (ds_read_b128): As row stride 272B, Bs 528B,
// offsets 32B/16B multiples -> aligned; As addr is ty-only (wave broadcast),
// Bs is 32 lanes x consecutive 16B (conflict-free).
template<int TRANSB, int ACT, int HASRES>
__global__ __launch_bounds__(256)
void gemm_k(const float* __restrict__ A, const float* __restrict__ W,
            const float* __restrict__ bias, const float* __restrict__ res,
            float resScale, float* __restrict__ C, int M, int N, int K) {
  __shared__ __align__(16) float As[BK][BM + 4];
  __shared__ __align__(16) float Bs[BK][BN + 4];
  int tid = threadIdx.x;
  int bm = blockIdx.y * BM, bn = blockIdx.x * BN;
  int tx = tid & 31, ty = tid >> 5;  // 32 x 8
  int r0 = ty * 8, c0 = tx * 4;
  float acc[8][4] = {};
  int aRow = tid >> 2, aK = (tid & 3) << 2;        // 64 rows x 4 quads
  int bRowN = tid >> 4, bColN = (tid & 15) << 3;   // NN: 16 rows x 8-wide
  int bNT = tid >> 1, bKT = (tid & 1) << 3;        // NT: 128 n x 8-wide k

  for (int bk = 0; bk < K; bk += BK) {
    float4 av = *(const float4*)(A + (size_t)(bm + aRow) * K + bk + aK);
    As[aK + 0][aRow] = av.x; As[aK + 1][aRow] = av.y;
    As[aK + 2][aRow] = av.z; As[aK + 3][aRow] = av.w;
    if (TRANSB) {
      const float* wp = W + (size_t)(bn + bNT) * K + bk + bKT;
      float4 b0 = *(const float4*)(wp);
      float4 b1 = *(const float4*)(wp + 4);
      Bs[bKT + 0][bNT] = b0.x; Bs[bKT + 1][bNT] = b0.y;
      Bs[bKT + 2][bNT] = b0.z; Bs[bKT + 3][bNT] = b0.w;
      Bs[bKT + 4][bNT] = b1.x; Bs[bKT + 5][bNT] = b1.y;
      Bs[bKT + 6][bNT] = b1.z; Bs[bKT + 7][bNT] = b1.w;
    } else {
      const float* wp = W + (size_t)(bk + bRowN) * N + bn + bColN;
      float4 b0 = *(const float4*)(wp);
      float4 b1 = *(const float4*)(wp + 4);
      float* dst = &Bs[bRowN][bColN];
      dst[0] = b0.x; dst[1] = b0.y; dst[2] = b0.z; dst[3] = b0.w;
      dst[4] = b1.x; dst[5] = b1.y; dst[6] = b1.z; dst[7] = b1.w;
    }
    __syncthreads();
    #pragma unroll
    for (int kk = 0; kk < BK; ++kk) {
      float4 a0 = *(const float4*)&As[kk][r0];
      float4 a1 = *(const float4*)&As[kk][r0 + 4];
      float4 bv = *(const float4*)&Bs[kk][c0];
      float a[8] = {a0.x, a0.y, a0.z, a0.w, a1.x, a1.y, a1.z, a1.w};
      float bf[4] = {bv.x, bv.y, bv.z, bv.w};
      #pragma unroll
      for (int i = 0; i < 8; ++i)
        #pragma unroll
        for (int j = 0; j < 4; ++j)
          acc[i][j] += a[i] * bf[j];
    }
    __syncthreads();
  }
  float bj[4];
  #pragma unroll
  for (int j = 0; j < 4; ++j) bj[j] = bias[bn + c0 + j];
  #pragma unroll
  for (int i = 0; i < 8; ++i) {
    size_t rowOff = (size_t)(bm + r0 + i) * N + bn + c0;
    #pragma unroll
    for (int j = 0; j < 4; ++j) {
      float v = acc[i][j] + bj[j];
      if (ACT == 1) v = geluf(v);
      if (HASRES) v = res[rowOff + j] + resScale * v;
      C[rowOff + j] = v;
    }
  }
}

// ---------------- rel-bias Toeplitz table: table[h][rel+1023] ----------------
__global__ __launch_bounds__(256)
void table_k(const float* __restrict__ rel_embed, float* __restrict__ table) {
  int idx = blockIdx.x * 256 + threadIdx.x;
  if (idx >= H_ * 2047) return;
  int h = idx / 2047, j = idx % 2047;
  int rel = j - 1023;
  int sign = rel >= 0 ? 1 : 0;
  int ap = rel >= 0 ? rel : -rel;
  int val;
  if (ap < 80) {
    val = ap;
  } else {
    float lr = logf((float)(ap > 1 ? ap : 1) / 80.f) / logf(10.f);
    int lp = (int)(80.f + lr * 80.f);
    val = lp < 159 ? lp : 159;
  }
  int bucket = val + sign * 160;
  bucket = bucket < 0 ? 0 : (bucket > 319 ? 319 : bucket);
  table[h * 2047 + j] = rel_embed[bucket * H_ + h];
}

// ---------------- attention: 8 q-rows per block ----------------
// softmax(q.k/8 + coef*table[s-t]) @ v ; coef from gate dots (fused)
// (reference's (a-max)*32/8 shift is softmax-invariant; folded away)
__global__ __launch_bounds__(256)
void attn_k(const float* __restrict__ qkv, const float* __restrict__ table,
            const float* __restrict__ gate_u, const float* __restrict__ gate_w,
            const float* __restrict__ scale_h, float* __restrict__ o) {
  __shared__ __align__(16) float sc[T_][12];   // scores [s][r], stride 48B (b128-ok)
  __shared__ __align__(16) float ored[4][8][DH_];
  int blk = blockIdx.x;
  int tb = blk & 127;           // T_/8 = 128 tiles
  int bh = blk >> 7;
  int h = bh & 7, b = bh >> 3;
  int t0 = tb * 8;
  int tid = threadIdx.x;
  const float* qkvb = qkv + (size_t)b * T_ * 1536;

  // Phase 1: scores. thread owns row r = tid&7, s-slots sl = tid>>3
  {
    int r = tid & 7;
    int t = t0 + r;
    float q[DH_];
    const float* qp = qkvb + (size_t)t * 1536 + h * 64;
    #pragma unroll
    for (int d4 = 0; d4 < 16; ++d4) {
      float4 v = *(const float4*)(qp + d4 * 4);
      q[d4 * 4] = v.x; q[d4 * 4 + 1] = v.y; q[d4 * 4 + 2] = v.z; q[d4 * 4 + 3] = v.w;
    }
    float gu = 0.f, gw = 0.f;
    #pragma unroll
    for (int d = 0; d < DH_; ++d) {
      gu += q[d] * gate_u[h * 64 + d];
      gw += q[d] * gate_w[h * 64 + d];
    }
    gu = sigmoidf_(gu);
    gw = sigmoidf_(gw);
    const float cf = 1.f + gu + (1.f - gu) * scale_h[h] * gw;
    const float* tab = table + h * 2047 + 1023 - t;
    int sl = tid >> 3;
    for (int i = 0; i < 32; ++i) {
      int s = sl + (i << 5);
      const float* kp = qkvb + (size_t)s * 1536 + 512 + h * 64;
      float acc = 0.f;
      #pragma unroll
      for (int d4 = 0; d4 < 16; ++d4) {
        float4 kv = *(const float4*)(kp + d4 * 4);
        acc += q[d4 * 4] * kv.x + q[d4 * 4 + 1] * kv.y
             + q[d4 * 4 + 2] * kv.z + q[d4 * 4 + 3] * kv.w;
      }
      sc[s][r] = acc * 0.125f + cf * tab[s];
    }
  }
  __syncthreads();
  // Phase 2: softmax per row; 32 lanes per row
  {
    int r = tid >> 5;
    int lane = tid & 31;
    float vals[32];
    float m = -1e30f;
    #pragma unroll
    for (int i = 0; i < 32; ++i) {
      vals[i] = sc[lane + (i << 5)][r];
      m = fmaxf(m, vals[i]);
    }
    #pragma unroll
    for (int off = 16; off > 0; off >>= 1)
      m = fmaxf(m, __shfl_xor(m, off, 32));
    float sum = 0.f;
    #pragma unroll
    for (int i = 0; i < 32; ++i) {
      vals[i] = expf(vals[i] - m);
      sum += vals[i];
    }
    #pragma unroll
    for (int off = 16; off > 0; off >>= 1)
      sum += __shfl_xor(sum, off, 32);
    float inv = 1.f / sum;
    #pragma unroll
    for (int i = 0; i < 32; ++i)
      sc[lane + (i << 5)][r] = vals[i] * inv;
  }
  __syncthreads();
  // Phase 3: PV. d = tid&63, chunk = tid>>6 (256 s each)
  {
    int d = tid & 63, chunk = tid >> 6;
    float acc[8] = {};
    for (int s = chunk * 256; s < chunk * 256 + 256; ++s) {
      float v = qkvb[(size_t)s * 1536 + 1024 + h * 64 + d];
      float4 p0 = *(const float4*)&sc[s][0];
      float4 p1 = *(const float4*)&sc[s][4];
      acc[0] += p0.x * v; acc[1] += p0.y * v; acc[2] += p0.z * v; acc[3] += p0.w * v;
      acc[4] += p1.x * v; acc[5] += p1.y * v; acc[6] += p1.z * v; acc[7] += p1.w * v;
    }
    #pragma unroll
    for (int r = 0; r < 8; ++r) ored[chunk][r][d] = acc[r];
  }
  __syncthreads();
  for (int idx = tid; idx < 8 * DH_; idx += 256) {
    int r = idx >> 6, d = idx & 63;
    float v = ored[0][r][d] + ored[1][r][d] + ored[2][r][d] + ored[3][r][d];
    o[((size_t)(b * T_ + t0 + r)) * DIM_ + h * 64 + d] = v;
  }
}

// ---------------- per-batch 2-moment reduction (atomic) ----------------
__global__ __launch_bounds__(256)
void gn_stats_k(const float* __restrict__ x, float* __restrict__ stats) {
  int b = blockIdx.y;
  const float* xb = x + (size_t)b * (DIM_ * T_);
  float s = 0.f, s2 = 0.f;
  for (int i = blockIdx.x * 256 + threadIdx.x; i < DIM_ * T_; i += 64 * 256) {
    float v = xb[i];
    s += v; s2 += v * v;
  }
  #pragma unroll
  for (int off = 32; off > 0; off >>= 1) {
    s += __shfl_xor(s, off);
    s2 += __shfl_xor(s2, off);
  }
  __shared__ float ps[4], ps2[4];
  int wid = threadIdx.x >> 6;
  if ((threadIdx.x & 63) == 0) { ps[wid] = s; ps2[wid] = s2; }
  __syncthreads();
  if (threadIdx.x == 0) {
    atomicAdd(&stats[b * 2],     ps[0] + ps[1] + ps[2] + ps[3]);
    atomicAdd(&stats[b * 2 + 1], ps2[0] + ps2[1] + ps2[2] + ps2[3]);
  }
}

// ---------------- groupnorm apply (+optional silu) ----------------
template<int SILU>
__global__ __launch_bounds__(256)
void gn_apply_k(const float* __restrict__ x, const float* __restrict__ stats,
                const float* __restrict__ g, const float* __restrict__ bt,
                float* __restrict__ y) {
  int i = blockIdx.x * 256 + threadIdx.x;      // 2M total
  int b = i >> 19;                             // 524288 per batch
  int c = i & (DIM_ - 1);
  const float cnt = 1.f / (float)(DIM_ * T_);
  float m = stats[b * 2] * cnt;
  float var = stats[b * 2 + 1] * cnt - m * m;
  float v = (x[i] - m) * rsqrtf(var + 1e-5f) * g[c] + bt[c];
  if (SILU) v = v * sigmoidf_(v);
  y[i] = v;
}

// ---------------- GLU: a * sigmoid(g) ----------------
__global__ __launch_bounds__(256)
void glu_k(const float* __restrict__ in, float* __restrict__ out) {
  int i = blockIdx.x * 256 + threadIdx.x;
  int btk = i >> 9, c = i & (DIM_ - 1);
  float a = in[(size_t)btk * 1024 + c];
  float gg = in[(size_t)btk * 1024 + 512 + c];
  out[i] = a * sigmoidf_(gg);
}

// ---------------- depthwise conv K=31, pad 15, (B,T,C) layout ----------------
__global__ __launch_bounds__(256)
void dwconv_k(const float* __restrict__ in, const float* __restrict__ w,
              const float* __restrict__ bias, float* __restrict__ out) {
  int c = blockIdx.x * 256 + threadIdx.x;
  int t = blockIdx.y, b = blockIdx.z;
  float acc = bias[c];
  #pragma unroll
  for (int k = 0; k < KW; ++k) {
    int tt = t + k - 15;
    if (tt >= 0 && tt < T_)
      acc += in[((size_t)b * T_ + tt) * DIM_ + c] * w[c * KW + k];
  }
  out[((size_t)b * T_ + t) * DIM_ + c] = acc;
}

extern "C" void kernel_launch(void* const* d_in, const int* in_sizes, int n_in,
                              void* d_out, int out_size, void* d_ws, size_t ws_size,
                              hipStream_t stream) {
  const float* x      = (const float*)d_in[0];
  const float* ff1_w1 = (const float*)d_in[1];
  const float* ff1_b1 = (const float*)d_in[2];
  const float* ff1_w2 = (const float*)d_in[3];
  const float* ff1_b2 = (const float*)d_in[4];
  const float* qkv_w  = (const float*)d_in[5];
  const float* qkv_b  = (const float*)d_in[6];
  const float* out_w  = (const float*)d_in[7];
  const float* out_b  = (const float*)d_in[8];
  const float* gn1_g  = (const float*)d_in[9];
  const float* gn1_b  = (const float*)d_in[10];
  const float* pw1_w  = (const float*)d_in[11];
  const float* pw1_b  = (const float*)d_in[12];
  const float* dw_w   = (const float*)d_in[13];
  const float* dw_b   = (const float*)d_in[14];
  const float* gn2_g  = (const float*)d_in[15];
  const float* gn2_b  = (const float*)d_in[16];
  const float* pw2_w  = (const float*)d_in[17];
  const float* pw2_b  = (const float*)d_in[18];
  const float* ff2_w1 = (const float*)d_in[19];
  const float* ff2_b1 = (const float*)d_in[20];
  const float* ff2_w2 = (const float*)d_in[21];
  const float* ff2_b2 = (const float*)d_in[22];
  const float* rel_embed = (const float*)d_in[23];
  const float* gate_u = (const float*)d_in[24];
  const float* gate_w = (const float*)d_in[25];
  const float* scale_h = (const float*)d_in[26];
  float* out = (float*)d_out;
  float* ws = (float*)d_ws;

  const int NTOK = B_ * T_;  // 4096
  // layout (floats): S0,S1,S2,S3 @ 2M each; O aliases S3 (disjoint live ranges);
  // BIGB 8.4M; TAB 16K; STATS 16.  Peak ~68 MB.
  float* S0   = ws;
  float* S1   = ws + 2097152;
  float* S2   = ws + 4194304;
  float* S3   = ws + 6291456;
  float* O    = S3;                  // alias: O dead before gn1 writes S3
  float* BIGB = ws + 8388608;
  float* TAB  = ws + 16777216;
  float* STATS = ws + 16793600;

  hipMemsetAsync(STATS, 0, 16 * sizeof(float), stream);

  dim3 tb(32, 8);
  // x (B,DIM,T) -> S0 (B,T,DIM)
  transpose_k<<<dim3(T_ / 32, DIM_ / 32, B_), tb, 0, stream>>>(x, S0, DIM_, T_);
  // FFN1
  gemm_k<0, 1, 0><<<dim3(FF_ / BN, NTOK / BM), 256, 0, stream>>>(
      S0, ff1_w1, ff1_b1, nullptr, 0.f, BIGB, NTOK, FF_, DIM_);
  gemm_k<0, 0, 1><<<dim3(DIM_ / BN, NTOK / BM), 256, 0, stream>>>(
      BIGB, ff1_w2, ff1_b2, S0, 0.5f, S1, NTOK, DIM_, FF_);
  // QKV
  gemm_k<0, 0, 0><<<dim3(1536 / BN, NTOK / BM), 256, 0, stream>>>(
      S1, qkv_w, qkv_b, nullptr, 0.f, BIGB, NTOK, 1536, DIM_);
  // rel-bias table + attention
  table_k<<<64, 256, 0, stream>>>(rel_embed, TAB);
  attn_k<<<B_ * H_ * (T_ / 8), 256, 0, stream>>>(BIGB, TAB, gate_u, gate_w, scale_h, O);
  // out proj + residual
  gemm_k<0, 0, 1><<<dim3(DIM_ / BN, NTOK / BM), 256, 0, stream>>>(
      O, out_w, out_b, S1, 1.f, S2, NTOK, DIM_, DIM_);
  // conv module
  gn_stats_k<<<dim3(64, B_), 256, 0, stream>>>(S2, STATS);
  gn_apply_k<0><<<8192, 256, 0, stream>>>(S2, STATS, gn1_g, gn1_b, S3);
  gemm_k<1, 0, 0><<<dim3(1024 / BN, NTOK / BM), 256, 0, stream>>>(
      S3, pw1_w, pw1_b, nullptr, 0.f, BIGB, NTOK, 1024, DIM_);
  glu_k<<<8192, 256, 0, stream>>>(BIGB, S0);
  dwconv_k<<<dim3(2, T_, B_), 256, 0, stream>>>(S0, dw_w, dw_b, S3);
  gn_stats_k<<<dim3(64, B_), 256, 0, stream>>>(S3, STATS + 8);
  gn_apply_k<1><<<8192, 256, 0, stream>>>(S3, STATS + 8, gn2_g, gn2_b, S0);
  gemm_k<1, 0, 1><<<dim3(DIM_ / BN, NTOK / BM), 256, 0, stream>>>(
      S0, pw2_w, pw2_b, S2, 1.f, S1, NTOK, DIM_, DIM_);
  // FFN2
  gemm_k<0, 1, 0><<<dim3(FF_ / BN, NTOK / BM), 256, 0, stream>>>(
      S1, ff2_w1, ff2_b1, nullptr, 0.f, BIGB, NTOK, FF_, DIM_);
  gemm_k<0, 0, 1><<<dim3(DIM_ / BN, NTOK / BM), 256, 0, stream>>>(
      BIGB, ff2_w2, ff2_b2, S1, 0.5f, S2, NTOK, DIM_, FF_);
  // S2 (B,T,DIM) -> out (B,DIM,T)
  transpose_k<<<dim3(DIM_ / 32, T_ / 32, B_), tb, 0, stream>>>(S2, out, T_, DIM_);
}

// Round 5
// 993.387 us; speedup vs baseline: 1.6316x; 1.6316x over previous
//
#include <hip/hip_runtime.h>
#include <math.h>

#define B_ 4
#define T_ 1024
#define DIM_ 512
#define H_ 8
#define DH_ 64
#define FF_ 2048
#define KW 31

typedef unsigned short u16;
typedef __attribute__((ext_vector_type(8))) short bf16x8;
typedef __attribute__((ext_vector_type(4))) float f32x4;

__device__ __forceinline__ float geluf(float x) {
  return 0.5f * x * (1.f + erff(x * 0.70710678118654752f));
}
__device__ __forceinline__ float sigmoidf_(float x) {
  return 1.f / (1.f + expf(-x));
}
__device__ __forceinline__ u16 f2bf(float f) {
  union { float f; unsigned int u; } v; v.f = f;
  unsigned int u = v.u;
  return (u16)((u + 0x7FFF + ((u >> 16) & 1)) >> 16);  // RNE
}

// ---------------- transpose (B,R,C) -> (B,C,R), fp32 out ----------------
__global__ __launch_bounds__(256)
void transpose_k(const float* __restrict__ in, float* __restrict__ out, int R, int C) {
  __shared__ float tile[32][33];
  int b = blockIdx.z;
  const float* ib = in + (size_t)b * R * C;
  float* ob = out + (size_t)b * R * C;
  int c0 = blockIdx.x * 32, r0 = blockIdx.y * 32;
  int tx = threadIdx.x, ty = threadIdx.y;
  for (int i = ty; i < 32; i += 8)
    tile[i][tx] = ib[(size_t)(r0 + i) * C + c0 + tx];
  __syncthreads();
  for (int i = ty; i < 32; i += 8)
    ob[(size_t)(c0 + i) * R + r0 + tx] = tile[tx][i];
}

// ---------------- transpose + dual write (fp32 + bf16) ----------------
__global__ __launch_bounds__(256)
void transpose_cvt_k(const float* __restrict__ in, float* __restrict__ out,
                     u16* __restrict__ outb, int R, int C) {
  __shared__ float tile[32][33];
  int b = blockIdx.z;
  const float* ib = in + (size_t)b * R * C;
  float* ob = out + (size_t)b * R * C;
  u16* ob2 = outb + (size_t)b * R * C;
  int c0 = blockIdx.x * 32, r0 = blockIdx.y * 32;
  int tx = threadIdx.x, ty = threadIdx.y;
  for (int i = ty; i < 32; i += 8)
    tile[i][tx] = ib[(size_t)(r0 + i) * C + c0 + tx];
  __syncthreads();
  for (int i = ty; i < 32; i += 8) {
    float v = tile[tx][i];
    size_t o = (size_t)(c0 + i) * R + r0 + tx;
    ob[o] = v;
    ob2[o] = f2bf(v);
  }
}

// ---------------- weight convert: [K,N] fp32 -> [N,K] bf16 ----------------
__global__ __launch_bounds__(256)
void wcvtT_k(const float* __restrict__ in, u16* __restrict__ out, int K, int N) {
  __shared__ float t[32][33];
  int n0 = blockIdx.x * 32, k0 = blockIdx.y * 32;
  int tx = threadIdx.x, ty = threadIdx.y;
  for (int i = ty; i < 32; i += 8)
    t[i][tx] = in[(size_t)(k0 + i) * N + n0 + tx];
  __syncthreads();
  for (int i = ty; i < 32; i += 8)
    out[(size_t)(n0 + i) * K + k0 + tx] = f2bf(t[tx][i]);
}

// ---------------- plain convert fp32 -> bf16 ----------------
__global__ __launch_bounds__(256)
void wcvt_k(const float* __restrict__ in, u16* __restrict__ out, int n) {
  int i = blockIdx.x * 256 + threadIdx.x;
  if (i < n) out[i] = f2bf(in[i]);
}

// ---------------- bf16 MFMA GEMM ----------------
// C[m,n] = (HASRES? res + resScale* : ) act( sum_k A[m,k]*Bt[n,k] + bias[n] )
// A [M,K] bf16 row-major, Bt [N,K] bf16 row-major (k-contiguous both sides).
// 128x128 tile, BK=32, 4 waves (2x2) x (4x4) mfma_f32_16x16x32_bf16 (m97 structure).
template<int ACT, int HASRES, int WF32, int WB16>
__global__ __launch_bounds__(256)
void bgemm_k(const u16* __restrict__ A, const u16* __restrict__ Bt,
             const float* __restrict__ bias, const float* __restrict__ res,
             float resScale, float* __restrict__ Cf, u16* __restrict__ Cb,
             int M, int N, int K) {
  __shared__ u16 As[128 * 32];
  __shared__ u16 Bs[128 * 32];
  int tid = threadIdx.x;
  int wave = tid >> 6, lane = tid & 63;
  int bm = blockIdx.y * 128, bn = blockIdx.x * 128;
  int wm = (wave >> 1) * 64, wn = (wave & 1) * 64;
  f32x4 acc[4][4];
  f32x4 zero = {0.f, 0.f, 0.f, 0.f};
  #pragma unroll
  for (int i = 0; i < 4; ++i)
    #pragma unroll
    for (int j = 0; j < 4; ++j) acc[i][j] = zero;

  // staging: tid t covers LDS bytes [t*16, t*16+16) == row t>>2, k-chunk (t&3)*8
  int srow = tid >> 2;
  int skc = (tid & 3) * 8;
  const u16* Ag = A + (size_t)(bm + srow) * K + skc;
  const u16* Bg = Bt + (size_t)(bn + srow) * K + skc;
  char* AsW = (char*)As + wave * 1024;  // wave-uniform LDS base
  char* BsW = (char*)Bs + wave * 1024;
  int fr = lane & 15, fk = (lane >> 4) * 8;

  for (int kt = 0; kt < K; kt += 32) {
    __builtin_amdgcn_global_load_lds(
        (const __attribute__((address_space(1))) void*)(Ag + kt),
        (__attribute__((address_space(3))) void*)AsW, 16, 0, 0);
    __builtin_amdgcn_global_load_lds(
        (const __attribute__((address_space(1))) void*)(Ag + kt + (size_t)64 * K),
        (__attribute__((address_space(3))) void*)(AsW + 4096), 16, 0, 0);
    __builtin_amdgcn_global_load_lds(
        (const __attribute__((address_space(1))) void*)(Bg + kt),
        (__attribute__((address_space(3))) void*)BsW, 16, 0, 0);
    __builtin_amdgcn_global_load_lds(
        (const __attribute__((address_space(1))) void*)(Bg + kt + (size_t)64 * K),
        (__attribute__((address_space(3))) void*)(BsW + 4096), 16, 0, 0);
    __syncthreads();  // compiler drains vmcnt before s_barrier
    bf16x8 af[4], bf[4];
    #pragma unroll
    for (int mi = 0; mi < 4; ++mi)
      af[mi] = *(const bf16x8*)(As + (wm + mi * 16 + fr) * 32 + fk);
    #pragma unroll
    for (int ni = 0; ni < 4; ++ni)
      bf[ni] = *(const bf16x8*)(Bs + (wn + ni * 16 + fr) * 32 + fk);
    #pragma unroll
    for (int mi = 0; mi < 4; ++mi)
      #pragma unroll
      for (int ni = 0; ni < 4; ++ni)
        acc[mi][ni] = __builtin_amdgcn_mfma_f32_16x16x32_bf16(
            af[mi], bf[ni], acc[mi][ni], 0, 0, 0);
    __syncthreads();
  }
  // C/D layout: col=lane&15, row=(lane>>4)*4+r (m89/m91 verified)
  int cr4 = (lane >> 4) * 4;
  int cc = lane & 15;
  #pragma unroll
  for (int mi = 0; mi < 4; ++mi) {
    #pragma unroll
    for (int r = 0; r < 4; ++r) {
      int row = bm + wm + mi * 16 + cr4 + r;
      size_t ro = (size_t)row * N;
      #pragma unroll
      for (int ni = 0; ni < 4; ++ni) {
        int c = bn + wn + ni * 16 + cc;
        float v = acc[mi][ni][r] + bias[c];
        if (ACT) v = geluf(v);
        if (HASRES) v = res[ro + c] + resScale * v;
        if (WF32) Cf[ro + c] = v;
        if (WB16) Cb[ro + c] = f2bf(v);
      }
    }
  }
}

// ---------------- rel-bias Toeplitz table: table[h][rel+1023] ----------------
__global__ __launch_bounds__(256)
void table_k(const float* __restrict__ rel_embed, float* __restrict__ table) {
  int idx = blockIdx.x * 256 + threadIdx.x;
  if (idx >= H_ * 2047) return;
  int h = idx / 2047, j = idx % 2047;
  int rel = j - 1023;
  int sign = rel >= 0 ? 1 : 0;
  int ap = rel >= 0 ? rel : -rel;
  int val;
  if (ap < 80) {
    val = ap;
  } else {
    float lr = logf((float)(ap > 1 ? ap : 1) / 80.f) / logf(10.f);
    int lp = (int)(80.f + lr * 80.f);
    val = lp < 159 ? lp : 159;
  }
  int bucket = val + sign * 160;
  bucket = bucket < 0 ? 0 : (bucket > 319 ? 319 : bucket);
  table[h * 2047 + j] = rel_embed[bucket * H_ + h];
}

// ---------------- attention: 8 q-rows per block (fp32 math, bf16 out) -------
__global__ __launch_bounds__(256)
void attn_k(const float* __restrict__ qkv, const float* __restrict__ table,
            const float* __restrict__ gate_u, const float* __restrict__ gate_w,
            const float* __restrict__ scale_h, u16* __restrict__ o) {
  __shared__ __align__(16) float sc[T_][12];
  __shared__ __align__(16) float ored[4][8][DH_];
  int blk = blockIdx.x;
  int tb = blk & 127;
  int bh = blk >> 7;
  int h = bh & 7, b = bh >> 3;
  int t0 = tb * 8;
  int tid = threadIdx.x;
  const float* qkvb = qkv + (size_t)b * T_ * 1536;

  {
    int r = tid & 7;
    int t = t0 + r;
    float q[DH_];
    const float* qp = qkvb + (size_t)t * 1536 + h * 64;
    #pragma unroll
    for (int d4 = 0; d4 < 16; ++d4) {
      float4 v = *(const float4*)(qp + d4 * 4);
      q[d4 * 4] = v.x; q[d4 * 4 + 1] = v.y; q[d4 * 4 + 2] = v.z; q[d4 * 4 + 3] = v.w;
    }
    float gu = 0.f, gw = 0.f;
    #pragma unroll
    for (int d = 0; d < DH_; ++d) {
      gu += q[d] * gate_u[h * 64 + d];
      gw += q[d] * gate_w[h * 64 + d];
    }
    gu = sigmoidf_(gu);
    gw = sigmoidf_(gw);
    const float cf = 1.f + gu + (1.f - gu) * scale_h[h] * gw;
    const float* tab = table + h * 2047 + 1023 - t;
    int sl = tid >> 3;
    for (int i = 0; i < 32; ++i) {
      int s = sl + (i << 5);
      const float* kp = qkvb + (size_t)s * 1536 + 512 + h * 64;
      float acc = 0.f;
      #pragma unroll
      for (int d4 = 0; d4 < 16; ++d4) {
        float4 kv = *(const float4*)(kp + d4 * 4);
        acc += q[d4 * 4] * kv.x + q[d4 * 4 + 1] * kv.y
             + q[d4 * 4 + 2] * kv.z + q[d4 * 4 + 3] * kv.w;
      }
      sc[s][r] = acc * 0.125f + cf * tab[s];
    }
  }
  __syncthreads();
  {
    int r = tid >> 5;
    int lane = tid & 31;
    float vals[32];
    float m = -1e30f;
    #pragma unroll
    for (int i = 0; i < 32; ++i) {
      vals[i] = sc[lane + (i << 5)][r];
      m = fmaxf(m, vals[i]);
    }
    #pragma unroll
    for (int off = 16; off > 0; off >>= 1)
      m = fmaxf(m, __shfl_xor(m, off, 32));
    float sum = 0.f;
    #pragma unroll
    for (int i = 0; i < 32; ++i) {
      vals[i] = expf(vals[i] - m);
      sum += vals[i];
    }
    #pragma unroll
    for (int off = 16; off > 0; off >>= 1)
      sum += __shfl_xor(sum, off, 32);
    float inv = 1.f / sum;
    #pragma unroll
    for (int i = 0; i < 32; ++i)
      sc[lane + (i << 5)][r] = vals[i] * inv;
  }
  __syncthreads();
  {
    int d = tid & 63, chunk = tid >> 6;
    float acc[8] = {};
    for (int s = chunk * 256; s < chunk * 256 + 256; ++s) {
      float v = qkvb[(size_t)s * 1536 + 1024 + h * 64 + d];
      float4 p0 = *(const float4*)&sc[s][0];
      float4 p1 = *(const float4*)&sc[s][4];
      acc[0] += p0.x * v; acc[1] += p0.y * v; acc[2] += p0.z * v; acc[3] += p0.w * v;
      acc[4] += p1.x * v; acc[5] += p1.y * v; acc[6] += p1.z * v; acc[7] += p1.w * v;
    }
    #pragma unroll
    for (int r = 0; r < 8; ++r) ored[chunk][r][d] = acc[r];
  }
  __syncthreads();
  for (int idx = tid; idx < 8 * DH_; idx += 256) {
    int r = idx >> 6, d = idx & 63;
    float v = ored[0][r][d] + ored[1][r][d] + ored[2][r][d] + ored[3][r][d];
    o[((size_t)(b * T_ + t0 + r)) * DIM_ + h * 64 + d] = f2bf(v);
  }
}

// ---------------- per-batch 2-moment reduction (atomic) ----------------
__global__ __launch_bounds__(256)
void gn_stats_k(const float* __restrict__ x, float* __restrict__ stats) {
  int b = blockIdx.y;
  const float* xb = x + (size_t)b * (DIM_ * T_);
  float s = 0.f, s2 = 0.f;
  for (int i = blockIdx.x * 256 + threadIdx.x; i < DIM_ * T_; i += 64 * 256) {
    float v = xb[i];
    s += v; s2 += v * v;
  }
  #pragma unroll
  for (int off = 32; off > 0; off >>= 1) {
    s += __shfl_xor(s, off);
    s2 += __shfl_xor(s2, off);
  }
  __shared__ float ps[4], ps2[4];
  int wid = threadIdx.x >> 6;
  if ((threadIdx.x & 63) == 0) { ps[wid] = s; ps2[wid] = s2; }
  __syncthreads();
  if (threadIdx.x == 0) {
    atomicAdd(&stats[b * 2],     ps[0] + ps[1] + ps[2] + ps[3]);
    atomicAdd(&stats[b * 2 + 1], ps2[0] + ps2[1] + ps2[2] + ps2[3]);
  }
}

// ---------------- groupnorm apply (+optional silu), bf16 out ----------------
template<int SILU>
__global__ __launch_bounds__(256)
void gn_apply_k(const float* __restrict__ x, const float* __restrict__ stats,
                const float* __restrict__ g, const float* __restrict__ bt,
                u16* __restrict__ y) {
  int i = blockIdx.x * 256 + threadIdx.x;
  int b = i >> 19;
  int c = i & (DIM_ - 1);
  const float cnt = 1.f / (float)(DIM_ * T_);
  float m = stats[b * 2] * cnt;
  float var = stats[b * 2 + 1] * cnt - m * m;
  float v = (x[i] - m) * rsqrtf(var + 1e-5f) * g[c] + bt[c];
  if (SILU) v = v * sigmoidf_(v);
  y[i] = f2bf(v);
}

// ---------------- GLU: a * sigmoid(g) ----------------
__global__ __launch_bounds__(256)
void glu_k(const float* __restrict__ in, float* __restrict__ out) {
  int i = blockIdx.x * 256 + threadIdx.x;
  int btk = i >> 9, c = i & (DIM_ - 1);
  float a = in[(size_t)btk * 1024 + c];
  float gg = in[(size_t)btk * 1024 + 512 + c];
  out[i] = a * sigmoidf_(gg);
}

// ---------------- depthwise conv K=31, pad 15, (B,T,C) layout ----------------
__global__ __launch_bounds__(256)
void dwconv_k(const float* __restrict__ in, const float* __restrict__ w,
              const float* __restrict__ bias, float* __restrict__ out) {
  int c = blockIdx.x * 256 + threadIdx.x;
  int t = blockIdx.y, b = blockIdx.z;
  float acc = bias[c];
  #pragma unroll
  for (int k = 0; k < KW; ++k) {
    int tt = t + k - 15;
    if (tt >= 0 && tt < T_)
      acc += in[((size_t)b * T_ + tt) * DIM_ + c] * w[c * KW + k];
  }
  out[((size_t)b * T_ + t) * DIM_ + c] = acc;
}

extern "C" void kernel_launch(void* const* d_in, const int* in_sizes, int n_in,
                              void* d_out, int out_size, void* d_ws, size_t ws_size,
                              hipStream_t stream) {
  const float* x      = (const float*)d_in[0];
  const float* ff1_w1 = (const float*)d_in[1];
  const float* ff1_b1 = (const float*)d_in[2];
  const float* ff1_w2 = (const float*)d_in[3];
  const float* ff1_b2 = (const float*)d_in[4];
  const float* qkv_w  = (const float*)d_in[5];
  const float* qkv_b  = (const float*)d_in[6];
  const float* out_w  = (const float*)d_in[7];
  const float* out_b  = (const float*)d_in[8];
  const float* gn1_g  = (const float*)d_in[9];
  const float* gn1_b  = (const float*)d_in[10];
  const float* pw1_w  = (const float*)d_in[11];
  const float* pw1_b  = (const float*)d_in[12];
  const float* dw_w   = (const float*)d_in[13];
  const float* dw_b   = (const float*)d_in[14];
  const float* gn2_g  = (const float*)d_in[15];
  const float* gn2_b  = (const float*)d_in[16];
  const float* pw2_w  = (const float*)d_in[17];
  const float* pw2_b  = (const float*)d_in[18];
  const float* ff2_w1 = (const float*)d_in[19];
  const float* ff2_b1 = (const float*)d_in[20];
  const float* ff2_w2 = (const float*)d_in[21];
  const float* ff2_b2 = (const float*)d_in[22];
  const float* rel_embed = (const float*)d_in[23];
  const float* gate_u = (const float*)d_in[24];
  const float* gate_w = (const float*)d_in[25];
  const float* scale_h = (const float*)d_in[26];
  float* out = (float*)d_out;
  float* ws = (float*)d_ws;

  // fp32 region (float offsets). S3 eliminated (dwconv reuses S1). Peak ~87.6 MB.
  float* S0    = ws;                  // 2M
  float* S1    = ws + 2097152;        // 2M
  float* S2    = ws + 4194304;        // 2M
  float* BIGB  = ws + 6291456;        // 6.3M (qkv out max)
  float* STATS = ws + 12582912;       // 16
  float* TAB   = ws + 12582928;       // 16384 -> ends 12599312
  // bf16 region (byte offset 50397248, 16B aligned)
  u16* B16    = (u16*)(ws + 12599312);
  u16* Ab     = B16;                  // 2M elems
  u16* Ab2    = B16 + 2097152;        // 2M
  u16* FFb    = B16 + 4194304;        // 8.4M
  u16* Wb     = B16 + 12582912;
  u16* ff1w1t = Wb;
  u16* ff1w2t = Wb + 1048576;
  u16* qkvwt  = Wb + 2097152;
  u16* outwt  = Wb + 2883584;
  u16* pw1wb  = Wb + 3145728;
  u16* pw2wb  = Wb + 3670016;
  u16* ff2w1t = Wb + 3932160;
  u16* ff2w2t = Wb + 4980736;         // ends Wb + 6029312

  hipMemsetAsync(STATS, 0, 16 * sizeof(float), stream);

  dim3 tb(32, 8);
  wcvtT_k<<<dim3(FF_ / 32, DIM_ / 32), tb, 0, stream>>>(ff1_w1, ff1w1t, DIM_, FF_);
  wcvtT_k<<<dim3(DIM_ / 32, FF_ / 32), tb, 0, stream>>>(ff1_w2, ff1w2t, FF_, DIM_);
  wcvtT_k<<<dim3(1536 / 32, DIM_ / 32), tb, 0, stream>>>(qkv_w, qkvwt, DIM_, 1536);
  wcvtT_k<<<dim3(DIM_ / 32, DIM_ / 32), tb, 0, stream>>>(out_w, outwt, DIM_, DIM_);
  wcvt_k<<<2048, 256, 0, stream>>>(pw1_w, pw1wb, 524288);
  wcvt_k<<<1024, 256, 0, stream>>>(pw2_w, pw2wb, 262144);
  wcvtT_k<<<dim3(FF_ / 32, DIM_ / 32), tb, 0, stream>>>(ff2_w1, ff2w1t, DIM_, FF_);
  wcvtT_k<<<dim3(DIM_ / 32, FF_ / 32), tb, 0, stream>>>(ff2_w2, ff2w2t, FF_, DIM_);
  table_k<<<64, 256, 0, stream>>>(rel_embed, TAB);

  // x (B,DIM,T) -> S0 fp32 + Ab bf16 (B,T,DIM)
  transpose_cvt_k<<<dim3(T_ / 32, DIM_ / 32, B_), tb, 0, stream>>>(x, S0, Ab, DIM_, T_);
  // FFN1
  bgemm_k<1, 0, 0, 1><<<dim3(16, 32), 256, 0, stream>>>(
      Ab, ff1w1t, ff1_b1, nullptr, 0.f, nullptr, FFb, 4096, FF_, DIM_);
  bgemm_k<0, 1, 1, 1><<<dim3(4, 32), 256, 0, stream>>>(
      FFb, ff1w2t, ff1_b2, S0, 0.5f, S1, Ab, 4096, DIM_, FF_);
  // QKV (fp32 out for fp32 attention)
  bgemm_k<0, 0, 1, 0><<<dim3(12, 32), 256, 0, stream>>>(
      Ab, qkvwt, qkv_b, nullptr, 0.f, BIGB, nullptr, 4096, 1536, DIM_);
  attn_k<<<B_ * H_ * (T_ / 8), 256, 0, stream>>>(BIGB, TAB, gate_u, gate_w, scale_h, Ab);
  // out proj + residual (S1 dead afterwards)
  bgemm_k<0, 1, 1, 0><<<dim3(4, 32), 256, 0, stream>>>(
      Ab, outwt, out_b, S1, 1.f, S2, nullptr, 4096, DIM_, DIM_);
  // conv module
  gn_stats_k<<<dim3(64, B_), 256, 0, stream>>>(S2, STATS);
  gn_apply_k<0><<<8192, 256, 0, stream>>>(S2, STATS, gn1_g, gn1_b, Ab);
  bgemm_k<0, 0, 1, 0><<<dim3(8, 32), 256, 0, stream>>>(
      Ab, pw1wb, pw1_b, nullptr, 0.f, BIGB, nullptr, 4096, 1024, DIM_);
  glu_k<<<8192, 256, 0, stream>>>(BIGB, S0);
  dwconv_k<<<dim3(2, T_, B_), 256, 0, stream>>>(S0, dw_w, dw_b, S1);  // S1 reused
  gn_stats_k<<<dim3(64, B_), 256, 0, stream>>>(S1, STATS + 8);
  gn_apply_k<1><<<8192, 256, 0, stream>>>(S1, STATS + 8, gn2_g, gn2_b, Ab);
  // pw2 + residual -> S1 fp32, Ab2 bf16 (Ab is this GEMM's A input)
  bgemm_k<0, 1, 1, 1><<<dim3(4, 32), 256, 0, stream>>>(
      Ab, pw2wb, pw2_b, S2, 1.f, S1, Ab2, 4096, DIM_, DIM_);
  // FFN2
  bgemm_k<1, 0, 0, 1><<<dim3(16, 32), 256, 0, stream>>>(
      Ab2, ff2w1t, ff2_b1, nullptr, 0.f, nullptr, FFb, 4096, FF_, DIM_);
  bgemm_k<0, 1, 1, 0><<<dim3(4, 32), 256, 0, stream>>>(
      FFb, ff2w2t, ff2_b2, S1, 0.5f, S2, nullptr, 4096, DIM_, FF_);
  transpose_k<<<dim3(DIM_ / 32, T_ / 32, B_), tb, 0, stream>>>(S2, out, T_, DIM_);
}

// Round 6
// 568.604 us; speedup vs baseline: 2.8505x; 1.7471x over previous
//
#include <hip/hip_runtime.h>
#include <math.h>

#define B_ 4
#define T_ 1024
#define DIM_ 512
#define H_ 8
#define DH_ 64
#define FF_ 2048
#define KW 31

typedef unsigned short u16;
typedef __attribute__((ext_vector_type(8))) short bf16x8;
typedef __attribute__((ext_vector_type(4))) float f32x4;

__device__ __forceinline__ float geluf(float x) {
  return 0.5f * x * (1.f + erff(x * 0.70710678118654752f));
}
__device__ __forceinline__ float sigmoidf_(float x) {
  return 1.f / (1.f + expf(-x));
}
__device__ __forceinline__ u16 f2bf(float f) {
  union { float f; unsigned int u; } v; v.f = f;
  unsigned int u = v.u;
  return (u16)((u + 0x7FFF + ((u >> 16) & 1)) >> 16);  // RNE
}

// ---------------- transpose (B,R,C) -> (B,C,R), fp32 out ----------------
__global__ __launch_bounds__(256)
void transpose_k(const float* __restrict__ in, float* __restrict__ out, int R, int C) {
  __shared__ float tile[32][33];
  int b = blockIdx.z;
  const float* ib = in + (size_t)b * R * C;
  float* ob = out + (size_t)b * R * C;
  int c0 = blockIdx.x * 32, r0 = blockIdx.y * 32;
  int tx = threadIdx.x, ty = threadIdx.y;
  for (int i = ty; i < 32; i += 8)
    tile[i][tx] = ib[(size_t)(r0 + i) * C + c0 + tx];
  __syncthreads();
  for (int i = ty; i < 32; i += 8)
    ob[(size_t)(c0 + i) * R + r0 + tx] = tile[tx][i];
}

// ---------------- transpose + dual write (fp32 + bf16) ----------------
__global__ __launch_bounds__(256)
void transpose_cvt_k(const float* __restrict__ in, float* __restrict__ out,
                     u16* __restrict__ outb, int R, int C) {
  __shared__ float tile[32][33];
  int b = blockIdx.z;
  const float* ib = in + (size_t)b * R * C;
  float* ob = out + (size_t)b * R * C;
  u16* ob2 = outb + (size_t)b * R * C;
  int c0 = blockIdx.x * 32, r0 = blockIdx.y * 32;
  int tx = threadIdx.x, ty = threadIdx.y;
  for (int i = ty; i < 32; i += 8)
    tile[i][tx] = ib[(size_t)(r0 + i) * C + c0 + tx];
  __syncthreads();
  for (int i = ty; i < 32; i += 8) {
    float v = tile[tx][i];
    size_t o = (size_t)(c0 + i) * R + r0 + tx;
    ob[o] = v;
    ob2[o] = f2bf(v);
  }
}

// ---------------- weight convert: [K,N] fp32 -> [N,K] bf16 ----------------
__global__ __launch_bounds__(256)
void wcvtT_k(const float* __restrict__ in, u16* __restrict__ out, int K, int N) {
  __shared__ float t[32][33];
  int n0 = blockIdx.x * 32, k0 = blockIdx.y * 32;
  int tx = threadIdx.x, ty = threadIdx.y;
  for (int i = ty; i < 32; i += 8)
    t[i][tx] = in[(size_t)(k0 + i) * N + n0 + tx];
  __syncthreads();
  for (int i = ty; i < 32; i += 8)
    out[(size_t)(n0 + i) * K + k0 + tx] = f2bf(t[tx][i]);
}

// ---------------- plain convert fp32 -> bf16 ----------------
__global__ __launch_bounds__(256)
void wcvt_k(const float* __restrict__ in, u16* __restrict__ out, int n) {
  int i = blockIdx.x * 256 + threadIdx.x;
  if (i < n) out[i] = f2bf(in[i]);
}

// ---------------- bf16 MFMA GEMM (unchanged, verified Round 5) ----------------
template<int ACT, int HASRES, int WF32, int WB16>
__global__ __launch_bounds__(256)
void bgemm_k(const u16* __restrict__ A, const u16* __restrict__ Bt,
             const float* __restrict__ bias, const float* __restrict__ res,
             float resScale, float* __restrict__ Cf, u16* __restrict__ Cb,
             int M, int N, int K) {
  __shared__ u16 As[128 * 32];
  __shared__ u16 Bs[128 * 32];
  int tid = threadIdx.x;
  int wave = tid >> 6, lane = tid & 63;
  int bm = blockIdx.y * 128, bn = blockIdx.x * 128;
  int wm = (wave >> 1) * 64, wn = (wave & 1) * 64;
  f32x4 acc[4][4];
  f32x4 zero = {0.f, 0.f, 0.f, 0.f};
  #pragma unroll
  for (int i = 0; i < 4; ++i)
    #pragma unroll
    for (int j = 0; j < 4; ++j) acc[i][j] = zero;

  int srow = tid >> 2;
  int skc = (tid & 3) * 8;
  const u16* Ag = A + (size_t)(bm + srow) * K + skc;
  const u16* Bg = Bt + (size_t)(bn + srow) * K + skc;
  char* AsW = (char*)As + wave * 1024;
  char* BsW = (char*)Bs + wave * 1024;
  int fr = lane & 15, fk = (lane >> 4) * 8;

  for (int kt = 0; kt < K; kt += 32) {
    __builtin_amdgcn_global_load_lds(
        (const __attribute__((address_space(1))) void*)(Ag + kt),
        (__attribute__((address_space(3))) void*)AsW, 16, 0, 0);
    __builtin_amdgcn_global_load_lds(
        (const __attribute__((address_space(1))) void*)(Ag + kt + (size_t)64 * K),
        (__attribute__((address_space(3))) void*)(AsW + 4096), 16, 0, 0);
    __builtin_amdgcn_global_load_lds(
        (const __attribute__((address_space(1))) void*)(Bg + kt),
        (__attribute__((address_space(3))) void*)BsW, 16, 0, 0);
    __builtin_amdgcn_global_load_lds(
        (const __attribute__((address_space(1))) void*)(Bg + kt + (size_t)64 * K),
        (__attribute__((address_space(3))) void*)(BsW + 4096), 16, 0, 0);
    __syncthreads();
    bf16x8 af[4], bf[4];
    #pragma unroll
    for (int mi = 0; mi < 4; ++mi)
      af[mi] = *(const bf16x8*)(As + (wm + mi * 16 + fr) * 32 + fk);
    #pragma unroll
    for (int ni = 0; ni < 4; ++ni)
      bf[ni] = *(const bf16x8*)(Bs + (wn + ni * 16 + fr) * 32 + fk);
    #pragma unroll
    for (int mi = 0; mi < 4; ++mi)
      #pragma unroll
      for (int ni = 0; ni < 4; ++ni)
        acc[mi][ni] = __builtin_amdgcn_mfma_f32_16x16x32_bf16(
            af[mi], bf[ni], acc[mi][ni], 0, 0, 0);
    __syncthreads();
  }
  int cr4 = (lane >> 4) * 4;
  int cc = lane & 15;
  #pragma unroll
  for (int mi = 0; mi < 4; ++mi) {
    #pragma unroll
    for (int r = 0; r < 4; ++r) {
      int row = bm + wm + mi * 16 + cr4 + r;
      size_t ro = (size_t)row * N;
      #pragma unroll
      for (int ni = 0; ni < 4; ++ni) {
        int c = bn + wn + ni * 16 + cc;
        float v = acc[mi][ni][r] + bias[c];
        if (ACT) v = geluf(v);
        if (HASRES) v = res[ro + c] + resScale * v;
        if (WF32) Cf[ro + c] = v;
        if (WB16) Cb[ro + c] = f2bf(v);
      }
    }
  }
}

// ---------------- rel-bias Toeplitz table: table[h][rel+1023] ----------------
__global__ __launch_bounds__(256)
void table_k(const float* __restrict__ rel_embed, float* __restrict__ table) {
  int idx = blockIdx.x * 256 + threadIdx.x;
  if (idx >= H_ * 2047) return;
  int h = idx / 2047, j = idx % 2047;
  int rel = j - 1023;
  int sign = rel >= 0 ? 1 : 0;
  int ap = rel >= 0 ? rel : -rel;
  int val;
  if (ap < 80) {
    val = ap;
  } else {
    float lr = logf((float)(ap > 1 ? ap : 1) / 80.f) / logf(10.f);
    int lp = (int)(80.f + lr * 80.f);
    val = lp < 159 ? lp : 159;
  }
  int bucket = val + sign * 160;
  bucket = bucket < 0 ? 0 : (bucket > 319 ? 319 : bucket);
  table[h * 2047 + j] = rel_embed[bucket * H_ + h];
}

// ---------------- QKV prep: fp32 [b,t,1536] -> Qb/Kb [bh,t,d], Vtb [bh,d,t] --
__global__ __launch_bounds__(256)
void qkv_prep_k(const float* __restrict__ qkv, u16* __restrict__ Qb,
                u16* __restrict__ Kb, u16* __restrict__ Vtb) {
  int i = blockIdx.x * 256 + threadIdx.x;  // 2M
  int b = i >> 19;
  int rem = i & 524287;
  int t = rem >> 9;
  int hd = rem & 511;
  int h = hd >> 6, d = hd & 63;
  int bh = b * 8 + h;
  const float* src = qkv + ((size_t)(b * 1024 + t)) * 1536 + hd;
  Qb[(size_t)bh * 65536 + t * 64 + d] = f2bf(src[0]);
  Kb[(size_t)bh * 65536 + t * 64 + d] = f2bf(src[512]);
  Vtb[((size_t)bh * 64 + d) * 1024 + t] = f2bf(src[1024]);
}

// ---------------- gate coefficients: CF[bh*1024+t] ----------------
__global__ __launch_bounds__(256)
void cf_k(const float* __restrict__ qkv, const float* __restrict__ gate_u,
          const float* __restrict__ gate_w, const float* __restrict__ scale_h,
          float* __restrict__ CF) {
  int j = blockIdx.x * 256 + threadIdx.x;  // 32768
  int bh = j >> 10, t = j & 1023;
  int h = bh & 7, b = bh >> 3;
  const float* q = qkv + ((size_t)(b * 1024 + t)) * 1536 + h * 64;
  float gu = 0.f, gw = 0.f;
  #pragma unroll
  for (int d4 = 0; d4 < 16; ++d4) {
    float4 qv = *(const float4*)(q + d4 * 4);
    float4 uv = *(const float4*)(gate_u + h * 64 + d4 * 4);
    float4 wv = *(const float4*)(gate_w + h * 64 + d4 * 4);
    gu += qv.x * uv.x + qv.y * uv.y + qv.z * uv.z + qv.w * uv.w;
    gw += qv.x * wv.x + qv.y * wv.y + qv.z * wv.z + qv.w * wv.w;
  }
  gu = sigmoidf_(gu);
  gw = sigmoidf_(gw);
  CF[j] = 1.f + gu + (1.f - gu) * scale_h[h] * gw;
}

// ---------------- MFMA flash attention ----------------
// block = (b,h,q-tile of 64); 4 waves x 16 q-rows.
// scores = QK^T/8 + cf*tab, online softmax, O += P.V via MFMA.
// K LDS [64s][64d], Vt LDS [64d][64s]: XOR-swizzled (src-preswizzle + read-XOR).
__global__ __launch_bounds__(256)
void attn_mfma_k(const u16* __restrict__ Qb, const u16* __restrict__ Kb,
                 const u16* __restrict__ Vtb, const float* __restrict__ CF,
                 const float* __restrict__ table, u16* __restrict__ o) {
  __shared__ u16 Ks[4096];    // 8 KB
  __shared__ u16 Vts[4096];   // 8 KB
  __shared__ u16 Ps[4096];    // 8 KB (wave-private rows)
  __shared__ float tabL[1104];
  int blk = blockIdx.x;
  int qt = blk & 15;
  int bh = blk >> 4;
  int h = bh & 7;
  int t0 = qt * 64;
  int tid = threadIdx.x;
  int wave = tid >> 6, lane = tid & 63;
  int w16 = wave * 16;
  int rg = lane >> 4;        // 0..3
  int ln = lane & 15;
  int qloc_a = w16 + ln;     // A-frag row
  int qloc_c = w16 + rg * 4; // C-frag row base (+r)

  for (int i = tid; i < 1087; i += 256)
    tabL[i] = table[h * 2047 + 960 - t0 + i];

  // Q A-fragments (k-steps d 0..31, 32..63)
  bf16x8 qf0, qf1;
  {
    const u16* Qg = Qb + ((size_t)bh * 1024 + t0 + qloc_a) * 64 + rg * 8;
    qf0 = *(const bf16x8*)(Qg);
    qf1 = *(const bf16x8*)(Qg + 32);
  }
  float cfr[4];
  #pragma unroll
  for (int r = 0; r < 4; ++r)
    cfr[r] = CF[(size_t)bh * 1024 + t0 + qloc_c + r];

  float mrow[4] = {-1e30f, -1e30f, -1e30f, -1e30f};
  float lrow[4] = {0.f, 0.f, 0.f, 0.f};
  f32x4 of[4];
  f32x4 zero = {0.f, 0.f, 0.f, 0.f};
  #pragma unroll
  for (int ni = 0; ni < 4; ++ni) of[ni] = zero;

  int srow0 = tid >> 3, sch = tid & 7;
  char* KsW = (char*)Ks + wave * 1024;
  char* VtsW = (char*)Vts + wave * 1024;

  for (int kt = 0; kt < 16; ++kt) {
    int s0 = kt * 64;
    // stage K [64s][64d] and Vt [64d][64s], src pre-swizzled (chunk ^ row&7)
    #pragma unroll
    for (int c = 0; c < 2; ++c) {
      int row = srow0 + c * 32;
      const u16* ksrc = Kb + ((size_t)bh * 1024 + s0 + row) * 64 + ((sch ^ (row & 7)) * 8);
      const u16* vsrc = Vtb + ((size_t)bh * 64 + row) * 1024 + s0 + ((sch ^ (row & 7)) * 8);
      __builtin_amdgcn_global_load_lds(
          (const __attribute__((address_space(1))) void*)ksrc,
          (__attribute__((address_space(3))) void*)(KsW + c * 4096), 16, 0, 0);
      __builtin_amdgcn_global_load_lds(
          (const __attribute__((address_space(1))) void*)vsrc,
          (__attribute__((address_space(3))) void*)(VtsW + c * 4096), 16, 0, 0);
    }
    __syncthreads();

    // QK^T: S[16q x 64s] per wave
    f32x4 sc4[4];
    #pragma unroll
    for (int ni = 0; ni < 4; ++ni) {
      int srow = ni * 16 + ln;
      const char* kr = (const char*)Ks + srow * 128;
      int x0 = (rg * 16) ^ ((srow & 7) << 4);
      int x1 = (rg * 16 + 64) ^ ((srow & 7) << 4);
      bf16x8 b0 = *(const bf16x8*)(kr + x0);
      bf16x8 b1 = *(const bf16x8*)(kr + x1);
      f32x4 a = __builtin_amdgcn_mfma_f32_16x16x32_bf16(qf0, b0, zero, 0, 0, 0);
      sc4[ni] = __builtin_amdgcn_mfma_f32_16x16x32_bf16(qf1, b1, a, 0, 0, 0);
    }

    // bias + online softmax
    float p[4][4], pm[4];
    #pragma unroll
    for (int r = 0; r < 4; ++r) pm[r] = -1e30f;
    #pragma unroll
    for (int ni = 0; ni < 4; ++ni) {
      int sl = ni * 16 + ln;
      #pragma unroll
      for (int r = 0; r < 4; ++r) {
        int dq = qloc_c + r;
        float v = sc4[ni][r] * 0.125f + cfr[r] * tabL[s0 + sl + 63 - dq];
        p[ni][r] = v;
        pm[r] = fmaxf(pm[r], v);
      }
    }
    float scl[4], rs[4];
    #pragma unroll
    for (int r = 0; r < 4; ++r) {
      float v = pm[r];
      v = fmaxf(v, __shfl_xor(v, 1));
      v = fmaxf(v, __shfl_xor(v, 2));
      v = fmaxf(v, __shfl_xor(v, 4));
      v = fmaxf(v, __shfl_xor(v, 8));
      float nm = fmaxf(mrow[r], v);
      scl[r] = expf(mrow[r] - nm);
      mrow[r] = nm;
      rs[r] = 0.f;
    }
    #pragma unroll
    for (int ni = 0; ni < 4; ++ni)
      #pragma unroll
      for (int r = 0; r < 4; ++r) {
        float e = expf(p[ni][r] - mrow[r]);
        p[ni][r] = e;
        rs[r] += e;
      }
    #pragma unroll
    for (int r = 0; r < 4; ++r) {
      float v = rs[r];
      v += __shfl_xor(v, 1);
      v += __shfl_xor(v, 2);
      v += __shfl_xor(v, 4);
      v += __shfl_xor(v, 8);
      lrow[r] = lrow[r] * scl[r] + v;
    }
    #pragma unroll
    for (int ni = 0; ni < 4; ++ni)
      #pragma unroll
      for (int r = 0; r < 4; ++r)
        of[ni][r] *= scl[r];

    // P -> LDS bf16 (wave-private rows, swizzled); then read A-frags
    #pragma unroll
    for (int ni = 0; ni < 4; ++ni) {
      int sl = ni * 16 + ln;
      #pragma unroll
      for (int r = 0; r < 4; ++r) {
        int row = qloc_c + r;
        int byi = (sl * 2) ^ ((row & 7) << 4);
        *(u16*)((char*)Ps + row * 128 + byi) = f2bf(p[ni][r]);
      }
    }
    bf16x8 pf0, pf1;
    {
      const char* pr = (const char*)Ps + qloc_a * 128;
      int x0 = (rg * 16) ^ ((qloc_a & 7) << 4);
      int x1 = (rg * 16 + 64) ^ ((qloc_a & 7) << 4);
      pf0 = *(const bf16x8*)(pr + x0);
      pf1 = *(const bf16x8*)(pr + x1);
    }
    // PV: O[16q x 64d] += P.V  (B-frag n=d from Vt[d][s], k=s contiguous)
    #pragma unroll
    for (int ni = 0; ni < 4; ++ni) {
      int drow = ni * 16 + ln;
      const char* vr = (const char*)Vts + drow * 128;
      int x0 = (rg * 16) ^ ((drow & 7) << 4);
      int x1 = (rg * 16 + 64) ^ ((drow & 7) << 4);
      bf16x8 v0 = *(const bf16x8*)(vr + x0);
      bf16x8 v1 = *(const bf16x8*)(vr + x1);
      of[ni] = __builtin_amdgcn_mfma_f32_16x16x32_bf16(pf0, v0, of[ni], 0, 0, 0);
      of[ni] = __builtin_amdgcn_mfma_f32_16x16x32_bf16(pf1, v1, of[ni], 0, 0, 0);
    }
    __syncthreads();
  }

  int b = bh >> 3;
  #pragma unroll
  for (int r = 0; r < 4; ++r) {
    float inv = 1.f / lrow[r];
    size_t ro = ((size_t)(b * 1024 + t0 + qloc_c + r)) * 512 + h * 64;
    #pragma unroll
    for (int ni = 0; ni < 4; ++ni)
      o[ro + ni * 16 + ln] = f2bf(of[ni][r] * inv);
  }
}

// ---------------- per-batch 2-moment reduction (atomic) ----------------
__global__ __launch_bounds__(256)
void gn_stats_k(const float* __restrict__ x, float* __restrict__ stats) {
  int b = blockIdx.y;
  const float* xb = x + (size_t)b * (DIM_ * T_);
  float s = 0.f, s2 = 0.f;
  for (int i = blockIdx.x * 256 + threadIdx.x; i < DIM_ * T_; i += 64 * 256) {
    float v = xb[i];
    s += v; s2 += v * v;
  }
  #pragma unroll
  for (int off = 32; off > 0; off >>= 1) {
    s += __shfl_xor(s, off);
    s2 += __shfl_xor(s2, off);
  }
  __shared__ float ps[4], ps2[4];
  int wid = threadIdx.x >> 6;
  if ((threadIdx.x & 63) == 0) { ps[wid] = s; ps2[wid] = s2; }
  __syncthreads();
  if (threadIdx.x == 0) {
    atomicAdd(&stats[b * 2],     ps[0] + ps[1] + ps[2] + ps[3]);
    atomicAdd(&stats[b * 2 + 1], ps2[0] + ps2[1] + ps2[2] + ps2[3]);
  }
}

// ---------------- groupnorm apply (+optional silu), bf16 out ----------------
template<int SILU>
__global__ __launch_bounds__(256)
void gn_apply_k(const float* __restrict__ x, const float* __restrict__ stats,
                const float* __restrict__ g, const float* __restrict__ bt,
                u16* __restrict__ y) {
  int i = blockIdx.x * 256 + threadIdx.x;
  int b = i >> 19;
  int c = i & (DIM_ - 1);
  const float cnt = 1.f / (float)(DIM_ * T_);
  float m = stats[b * 2] * cnt;
  float var = stats[b * 2 + 1] * cnt - m * m;
  float v = (x[i] - m) * rsqrtf(var + 1e-5f) * g[c] + bt[c];
  if (SILU) v = v * sigmoidf_(v);
  y[i] = f2bf(v);
}

// ---------------- GLU: a * sigmoid(g) ----------------
__global__ __launch_bounds__(256)
void glu_k(const float* __restrict__ in, float* __restrict__ out) {
  int i = blockIdx.x * 256 + threadIdx.x;
  int btk = i >> 9, c = i & (DIM_ - 1);
  float a = in[(size_t)btk * 1024 + c];
  float gg = in[(size_t)btk * 1024 + 512 + c];
  out[i] = a * sigmoidf_(gg);
}

// ---------------- depthwise conv K=31, pad 15, (B,T,C) layout ----------------
__global__ __launch_bounds__(256)
void dwconv_k(const float* __restrict__ in, const float* __restrict__ w,
              const float* __restrict__ bias, float* __restrict__ out) {
  int c = blockIdx.x * 256 + threadIdx.x;
  int t = blockIdx.y, b = blockIdx.z;
  float acc = bias[c];
  #pragma unroll
  for (int k = 0; k < KW; ++k) {
    int tt = t + k - 15;
    if (tt >= 0 && tt < T_)
      acc += in[((size_t)b * T_ + tt) * DIM_ + c] * w[c * KW + k];
  }
  out[((size_t)b * T_ + t) * DIM_ + c] = acc;
}

extern "C" void kernel_launch(void* const* d_in, const int* in_sizes, int n_in,
                              void* d_out, int out_size, void* d_ws, size_t ws_size,
                              hipStream_t stream) {
  const float* x      = (const float*)d_in[0];
  const float* ff1_w1 = (const float*)d_in[1];
  const float* ff1_b1 = (const float*)d_in[2];
  const float* ff1_w2 = (const float*)d_in[3];
  const float* ff1_b2 = (const float*)d_in[4];
  const float* qkv_w  = (const float*)d_in[5];
  const float* qkv_b  = (const float*)d_in[6];
  const float* out_w  = (const float*)d_in[7];
  const float* out_b  = (const float*)d_in[8];
  const float* gn1_g  = (const float*)d_in[9];
  const float* gn1_b  = (const float*)d_in[10];
  const float* pw1_w  = (const float*)d_in[11];
  const float* pw1_b  = (const float*)d_in[12];
  const float* dw_w   = (const float*)d_in[13];
  const float* dw_b   = (const float*)d_in[14];
  const float* gn2_g  = (const float*)d_in[15];
  const float* gn2_b  = (const float*)d_in[16];
  const float* pw2_w  = (const float*)d_in[17];
  const float* pw2_b  = (const float*)d_in[18];
  const float* ff2_w1 = (const float*)d_in[19];
  const float* ff2_b1 = (const float*)d_in[20];
  const float* ff2_w2 = (const float*)d_in[21];
  const float* ff2_b2 = (const float*)d_in[22];
  const float* rel_embed = (const float*)d_in[23];
  const float* gate_u = (const float*)d_in[24];
  const float* gate_w = (const float*)d_in[25];
  const float* scale_h = (const float*)d_in[26];
  float* out = (float*)d_out;
  float* ws = (float*)d_ws;

  // fp32 region (float offsets)
  float* S0    = ws;                  // 2M
  float* S1    = ws + 2097152;        // 2M
  float* S2    = ws + 4194304;        // 2M
  float* BIGB  = ws + 6291456;        // 6.3M (qkv out)
  float* STATS = ws + 12582912;       // 16
  float* TAB   = ws + 12582928;       // 16384
  float* CF    = ws + 12599312;       // 32768 -> ends 12632080
  // bf16 region
  u16* B16    = (u16*)(ws + 12632080);
  u16* Ab     = B16;                  // 2M elems
  u16* Ab2    = B16 + 2097152;        // 2M
  u16* FFb    = B16 + 4194304;        // 8.4M
  u16* Qb     = FFb;                  // alias: FFb dead between FFN1 and FFN2
  u16* Kb     = FFb + 2097152;
  u16* Vtb    = FFb + 4194304;
  u16* Wb     = B16 + 12582912;
  u16* ff1w1t = Wb;
  u16* ff1w2t = Wb + 1048576;
  u16* qkvwt  = Wb + 2097152;
  u16* outwt  = Wb + 2883584;
  u16* pw1wb  = Wb + 3145728;
  u16* pw2wb  = Wb + 3670016;
  u16* ff2w1t = Wb + 3932160;
  u16* ff2w2t = Wb + 4980736;         // ends Wb + 6029312

  hipMemsetAsync(STATS, 0, 16 * sizeof(float), stream);

  dim3 tb(32, 8);
  wcvtT_k<<<dim3(FF_ / 32, DIM_ / 32), tb, 0, stream>>>(ff1_w1, ff1w1t, DIM_, FF_);
  wcvtT_k<<<dim3(DIM_ / 32, FF_ / 32), tb, 0, stream>>>(ff1_w2, ff1w2t, FF_, DIM_);
  wcvtT_k<<<dim3(1536 / 32, DIM_ / 32), tb, 0, stream>>>(qkv_w, qkvwt, DIM_, 1536);
  wcvtT_k<<<dim3(DIM_ / 32, DIM_ / 32), tb, 0, stream>>>(out_w, outwt, DIM_, DIM_);
  wcvt_k<<<2048, 256, 0, stream>>>(pw1_w, pw1wb, 524288);
  wcvt_k<<<1024, 256, 0, stream>>>(pw2_w, pw2wb, 262144);
  wcvtT_k<<<dim3(FF_ / 32, DIM_ / 32), tb, 0, stream>>>(ff2_w1, ff2w1t, DIM_, FF_);
  wcvtT_k<<<dim3(DIM_ / 32, FF_ / 32), tb, 0, stream>>>(ff2_w2, ff2w2t, FF_, DIM_);
  table_k<<<64, 256, 0, stream>>>(rel_embed, TAB);

  // x (B,DIM,T) -> S0 fp32 + Ab bf16 (B,T,DIM)
  transpose_cvt_k<<<dim3(T_ / 32, DIM_ / 32, B_), tb, 0, stream>>>(x, S0, Ab, DIM_, T_);
  // FFN1
  bgemm_k<1, 0, 0, 1><<<dim3(16, 32), 256, 0, stream>>>(
      Ab, ff1w1t, ff1_b1, nullptr, 0.f, nullptr, FFb, 4096, FF_, DIM_);
  bgemm_k<0, 1, 1, 1><<<dim3(4, 32), 256, 0, stream>>>(
      FFb, ff1w2t, ff1_b2, S0, 0.5f, S1, Ab, 4096, DIM_, FF_);
  // QKV (fp32 out)
  bgemm_k<0, 0, 1, 0><<<dim3(12, 32), 256, 0, stream>>>(
      Ab, qkvwt, qkv_b, nullptr, 0.f, BIGB, nullptr, 4096, 1536, DIM_);
  // attention prep + MFMA flash attention -> Ab bf16
  qkv_prep_k<<<8192, 256, 0, stream>>>(BIGB, Qb, Kb, Vtb);
  cf_k<<<128, 256, 0, stream>>>(BIGB, gate_u, gate_w, scale_h, CF);
  attn_mfma_k<<<512, 256, 0, stream>>>(Qb, Kb, Vtb, CF, TAB, Ab);
  // out proj + residual (S1 dead afterwards)
  bgemm_k<0, 1, 1, 0><<<dim3(4, 32), 256, 0, stream>>>(
      Ab, outwt, out_b, S1, 1.f, S2, nullptr, 4096, DIM_, DIM_);
  // conv module
  gn_stats_k<<<dim3(64, B_), 256, 0, stream>>>(S2, STATS);
  gn_apply_k<0><<<8192, 256, 0, stream>>>(S2, STATS, gn1_g, gn1_b, Ab);
  bgemm_k<0, 0, 1, 0><<<dim3(8, 32), 256, 0, stream>>>(
      Ab, pw1wb, pw1_b, nullptr, 0.f, BIGB, nullptr, 4096, 1024, DIM_);
  glu_k<<<8192, 256, 0, stream>>>(BIGB, S0);
  dwconv_k<<<dim3(2, T_, B_), 256, 0, stream>>>(S0, dw_w, dw_b, S1);
  gn_stats_k<<<dim3(64, B_), 256, 0, stream>>>(S1, STATS + 8);
  gn_apply_k<1><<<8192, 256, 0, stream>>>(S1, STATS + 8, gn2_g, gn2_b, Ab);
  // pw2 + residual -> S1 fp32, Ab2 bf16
  bgemm_k<0, 1, 1, 1><<<dim3(4, 32), 256, 0, stream>>>(
      Ab, pw2wb, pw2_b, S2, 1.f, S1, Ab2, 4096, DIM_, DIM_);
  // FFN2
  bgemm_k<1, 0, 0, 1><<<dim3(16, 32), 256, 0, stream>>>(
      Ab2, ff2w1t, ff2_b1, nullptr, 0.f, nullptr, FFb, 4096, FF_, DIM_);
  bgemm_k<0, 1, 1, 0><<<dim3(4, 32), 256, 0, stream>>>(
      FFb, ff2w2t, ff2_b2, S1, 0.5f, S2, nullptr, 4096, DIM_, FF_);
  transpose_k<<<dim3(DIM_ / 32, T_ / 32, B_), tb, 0, stream>>>(S2, out, T_, DIM_);
}

// Round 11
// 485.239 us; speedup vs baseline: 3.3402x; 1.1718x over previous
//
#include <hip/hip_runtime.h>
#include <math.h>

#define B_ 4
#define T_ 1024
#define DIM_ 512
#define H_ 8
#define DH_ 64
#define FF_ 2048
#define KW 31
#define DCT 16   // dwconv t-outputs per thread

typedef unsigned short u16;
typedef __attribute__((ext_vector_type(8))) short bf16x8;
typedef __attribute__((ext_vector_type(4))) float f32x4;

__device__ __forceinline__ float geluf(float x) {
  return 0.5f * x * (1.f + erff(x * 0.70710678118654752f));
}
__device__ __forceinline__ float sigmoidf_(float x) {
  return 1.f / (1.f + expf(-x));
}
__device__ __forceinline__ u16 f2bf(float f) {
  union { float f; unsigned int u; } v; v.f = f;
  unsigned int u = v.u;
  return (u16)((u + 0x7FFF + ((u >> 16) & 1)) >> 16);  // RNE
}

// ---------------- transpose (B,R,C) -> (B,C,R), fp32 out ----------------
__global__ __launch_bounds__(256)
void transpose_k(const float* __restrict__ in, float* __restrict__ out, int R, int C) {
  __shared__ float tile[32][33];
  int b = blockIdx.z;
  const float* ib = in + (size_t)b * R * C;
  float* ob = out + (size_t)b * R * C;
  int c0 = blockIdx.x * 32, r0 = blockIdx.y * 32;
  int tx = threadIdx.x, ty = threadIdx.y;
  for (int i = ty; i < 32; i += 8)
    tile[i][tx] = ib[(size_t)(r0 + i) * C + c0 + tx];
  __syncthreads();
  for (int i = ty; i < 32; i += 8)
    ob[(size_t)(c0 + i) * R + r0 + tx] = tile[tx][i];
}

// ---------------- transpose + dual write (fp32 + bf16) ----------------
__global__ __launch_bounds__(256)
void transpose_cvt_k(const float* __restrict__ in, float* __restrict__ out,
                     u16* __restrict__ outb, int R, int C) {
  __shared__ float tile[32][33];
  int b = blockIdx.z;
  const float* ib = in + (size_t)b * R * C;
  float* ob = out + (size_t)b * R * C;
  u16* ob2 = outb + (size_t)b * R * C;
  int c0 = blockIdx.x * 32, r0 = blockIdx.y * 32;
  int tx = threadIdx.x, ty = threadIdx.y;
  for (int i = ty; i < 32; i += 8)
    tile[i][tx] = ib[(size_t)(r0 + i) * C + c0 + tx];
  __syncthreads();
  for (int i = ty; i < 32; i += 8) {
    float v = tile[tx][i];
    size_t o = (size_t)(c0 + i) * R + r0 + tx;
    ob[o] = v;
    ob2[o] = f2bf(v);
  }
}

// ---------------- weight convert: [K,N] fp32 -> [N,K] bf16 ----------------
__global__ __launch_bounds__(256)
void wcvtT_k(const float* __restrict__ in, u16* __restrict__ out, int K, int N) {
  __shared__ float t[32][33];
  int n0 = blockIdx.x * 32, k0 = blockIdx.y * 32;
  int tx = threadIdx.x, ty = threadIdx.y;
  for (int i = ty; i < 32; i += 8)
    t[i][tx] = in[(size_t)(k0 + i) * N + n0 + tx];
  __syncthreads();
  for (int i = ty; i < 32; i += 8)
    out[(size_t)(n0 + i) * K + k0 + tx] = f2bf(t[tx][i]);
}

// ---------------- plain convert fp32 -> bf16 ----------------
__global__ __launch_bounds__(256)
void wcvt_k(const float* __restrict__ in, u16* __restrict__ out, int n) {
  int i = blockIdx.x * 256 + threadIdx.x;
  if (i < n) out[i] = f2bf(in[i]);
}

// ---------------- bf16 MFMA GEMM (verified Round 5) ----------------
template<int ACT, int HASRES, int WF32, int WB16>
__global__ __launch_bounds__(256)
void bgemm_k(const u16* __restrict__ A, const u16* __restrict__ Bt,
             const float* __restrict__ bias, const float* __restrict__ res,
             float resScale, float* __restrict__ Cf, u16* __restrict__ Cb,
             int M, int N, int K) {
  __shared__ u16 As[128 * 32];
  __shared__ u16 Bs[128 * 32];
  int tid = threadIdx.x;
  int wave = tid >> 6, lane = tid & 63;
  int bm = blockIdx.y * 128, bn = blockIdx.x * 128;
  int wm = (wave >> 1) * 64, wn = (wave & 1) * 64;
  f32x4 acc[4][4];
  f32x4 zero = {0.f, 0.f, 0.f, 0.f};
  #pragma unroll
  for (int i = 0; i < 4; ++i)
    #pragma unroll
    for (int j = 0; j < 4; ++j) acc[i][j] = zero;

  int srow = tid >> 2;
  int skc = (tid & 3) * 8;
  const u16* Ag = A + (size_t)(bm + srow) * K + skc;
  const u16* Bg = Bt + (size_t)(bn + srow) * K + skc;
  char* AsW = (char*)As + wave * 1024;
  char* BsW = (char*)Bs + wave * 1024;
  int fr = lane & 15, fk = (lane >> 4) * 8;

  for (int kt = 0; kt < K; kt += 32) {
    __builtin_amdgcn_global_load_lds(
        (const __attribute__((address_space(1))) void*)(Ag + kt),
        (__attribute__((address_space(3))) void*)AsW, 16, 0, 0);
    __builtin_amdgcn_global_load_lds(
        (const __attribute__((address_space(1))) void*)(Ag + kt + (size_t)64 * K),
        (__attribute__((address_space(3))) void*)(AsW + 4096), 16, 0, 0);
    __builtin_amdgcn_global_load_lds(
        (const __attribute__((address_space(1))) void*)(Bg + kt),
        (__attribute__((address_space(3))) void*)BsW, 16, 0, 0);
    __builtin_amdgcn_global_load_lds(
        (const __attribute__((address_space(1))) void*)(Bg + kt + (size_t)64 * K),
        (__attribute__((address_space(3))) void*)(BsW + 4096), 16, 0, 0);
    __syncthreads();
    bf16x8 af[4], bf[4];
    #pragma unroll
    for (int mi = 0; mi < 4; ++mi)
      af[mi] = *(const bf16x8*)(As + (wm + mi * 16 + fr) * 32 + fk);
    #pragma unroll
    for (int ni = 0; ni < 4; ++ni)
      bf[ni] = *(const bf16x8*)(Bs + (wn + ni * 16 + fr) * 32 + fk);
    #pragma unroll
    for (int mi = 0; mi < 4; ++mi)
      #pragma unroll
      for (int ni = 0; ni < 4; ++ni)
        acc[mi][ni] = __builtin_amdgcn_mfma_f32_16x16x32_bf16(
            af[mi], bf[ni], acc[mi][ni], 0, 0, 0);
    __syncthreads();
  }
  int cr4 = (lane >> 4) * 4;
  int cc = lane & 15;
  #pragma unroll
  for (int mi = 0; mi < 4; ++mi) {
    #pragma unroll
    for (int r = 0; r < 4; ++r) {
      int row = bm + wm + mi * 16 + cr4 + r;
      size_t ro = (size_t)row * N;
      #pragma unroll
      for (int ni = 0; ni < 4; ++ni) {
        int c = bn + wn + ni * 16 + cc;
        float v = acc[mi][ni][r] + bias[c];
        if (ACT) v = geluf(v);
        if (HASRES) v = res[ro + c] + resScale * v;
        if (WF32) Cf[ro + c] = v;
        if (WB16) Cb[ro + c] = f2bf(v);
      }
    }
  }
}

// ---------------- rel-bias Toeplitz table: table[h][rel+1023] ----------------
__global__ __launch_bounds__(256)
void table_k(const float* __restrict__ rel_embed, float* __restrict__ table) {
  int idx = blockIdx.x * 256 + threadIdx.x;
  if (idx >= H_ * 2047) return;
  int h = idx / 2047, j = idx % 2047;
  int rel = j - 1023;
  int sign = rel >= 0 ? 1 : 0;
  int ap = rel >= 0 ? rel : -rel;
  int val;
  if (ap < 80) {
    val = ap;
  } else {
    float lr = logf((float)(ap > 1 ? ap : 1) / 80.f) / logf(10.f);
    int lp = (int)(80.f + lr * 80.f);
    val = lp < 159 ? lp : 159;
  }
  int bucket = val + sign * 160;
  bucket = bucket < 0 ? 0 : (bucket > 319 ? 319 : bucket);
  table[h * 2047 + j] = rel_embed[bucket * H_ + h];
}

// ---------------- QKV prep (coalesced): block = (bh, 64-t tile) ----------------
// Qb/Kb [bh,t,d] straight cvt; Vt via padded LDS tile, t-major coalesced store.
__global__ __launch_bounds__(256)
void qkv_prep_k(const float* __restrict__ qkv, u16* __restrict__ Qb,
                u16* __restrict__ Kb, u16* __restrict__ Vtb) {
  __shared__ float vt[64][65];
  int bh = blockIdx.x;
  int h = bh & 7, b = bh >> 3;
  int t0 = blockIdx.y * 64;
  int tid = threadIdx.x;
  int d = tid & 63, tr = tid >> 6;
  #pragma unroll
  for (int i = 0; i < 16; ++i) {
    int t = i * 4 + tr;
    const float* src = qkv + ((size_t)(b * 1024 + t0 + t)) * 1536 + h * 64 + d;
    size_t o = (size_t)bh * 65536 + (t0 + t) * 64 + d;
    Qb[o] = f2bf(src[0]);
    Kb[o] = f2bf(src[512]);
    vt[t][d] = src[1024];
  }
  __syncthreads();
  int tl = tid & 63, dr = tid >> 6;
  #pragma unroll
  for (int i = 0; i < 16; ++i) {
    int dd = i * 4 + dr;
    Vtb[((size_t)bh * 64 + dd) * 1024 + t0 + tl] = f2bf(vt[tl][dd]);
  }
}

// ---------------- gate coefficients: CF[bh*1024+t] ----------------
__global__ __launch_bounds__(256)
void cf_k(const float* __restrict__ qkv, const float* __restrict__ gate_u,
          const float* __restrict__ gate_w, const float* __restrict__ scale_h,
          float* __restrict__ CF) {
  int j = blockIdx.x * 256 + threadIdx.x;  // 32768
  int bh = j >> 10, t = j & 1023;
  int h = bh & 7, b = bh >> 3;
  const float* q = qkv + ((size_t)(b * 1024 + t)) * 1536 + h * 64;
  float gu = 0.f, gw = 0.f;
  #pragma unroll
  for (int d4 = 0; d4 < 16; ++d4) {
    float4 qv = *(const float4*)(q + d4 * 4);
    float4 uv = *(const float4*)(gate_u + h * 64 + d4 * 4);
    float4 wv = *(const float4*)(gate_w + h * 64 + d4 * 4);
    gu += qv.x * uv.x + qv.y * uv.y + qv.z * uv.z + qv.w * uv.w;
    gw += qv.x * wv.x + qv.y * wv.y + qv.z * wv.z + qv.w * wv.w;
  }
  gu = sigmoidf_(gu);
  gw = sigmoidf_(gw);
  CF[j] = 1.f + gu + (1.f - gu) * scale_h[h] * gw;
}

// ---------------- MFMA flash attention (verified Round 6) ----------------
__global__ __launch_bounds__(256)
void attn_mfma_k(const u16* __restrict__ Qb, const u16* __restrict__ Kb,
                 const u16* __restrict__ Vtb, const float* __restrict__ CF,
                 const float* __restrict__ table, u16* __restrict__ o) {
  __shared__ u16 Ks[4096];
  __shared__ u16 Vts[4096];
  __shared__ u16 Ps[4096];
  __shared__ float tabL[1104];
  int blk = blockIdx.x;
  int qt = blk & 15;
  int bh = blk >> 4;
  int h = bh & 7;
  int t0 = qt * 64;
  int tid = threadIdx.x;
  int wave = tid >> 6, lane = tid & 63;
  int w16 = wave * 16;
  int rg = lane >> 4;
  int ln = lane & 15;
  int qloc_a = w16 + ln;
  int qloc_c = w16 + rg * 4;

  for (int i = tid; i < 1087; i += 256)
    tabL[i] = table[h * 2047 + 960 - t0 + i];

  bf16x8 qf0, qf1;
  {
    const u16* Qg = Qb + ((size_t)bh * 1024 + t0 + qloc_a) * 64 + rg * 8;
    qf0 = *(const bf16x8*)(Qg);
    qf1 = *(const bf16x8*)(Qg + 32);
  }
  float cfr[4];
  #pragma unroll
  for (int r = 0; r < 4; ++r)
    cfr[r] = CF[(size_t)bh * 1024 + t0 + qloc_c + r];

  float mrow[4] = {-1e30f, -1e30f, -1e30f, -1e30f};
  float lrow[4] = {0.f, 0.f, 0.f, 0.f};
  f32x4 of[4];
  f32x4 zero = {0.f, 0.f, 0.f, 0.f};
  #pragma unroll
  for (int ni = 0; ni < 4; ++ni) of[ni] = zero;

  int srow0 = tid >> 3, sch = tid & 7;
  char* KsW = (char*)Ks + wave * 1024;
  char* VtsW = (char*)Vts + wave * 1024;

  for (int kt = 0; kt < 16; ++kt) {
    int s0 = kt * 64;
    #pragma unroll
    for (int c = 0; c < 2; ++c) {
      int row = srow0 + c * 32;
      const u16* ksrc = Kb + ((size_t)bh * 1024 + s0 + row) * 64 + ((sch ^ (row & 7)) * 8);
      const u16* vsrc = Vtb + ((size_t)bh * 64 + row) * 1024 + s0 + ((sch ^ (row & 7)) * 8);
      __builtin_amdgcn_global_load_lds(
          (const __attribute__((address_space(1))) void*)ksrc,
          (__attribute__((address_space(3))) void*)(KsW + c * 4096), 16, 0, 0);
      __builtin_amdgcn_global_load_lds(
          (const __attribute__((address_space(1))) void*)vsrc,
          (__attribute__((address_space(3))) void*)(VtsW + c * 4096), 16, 0, 0);
    }
    __syncthreads();

    f32x4 sc4[4];
    #pragma unroll
    for (int ni = 0; ni < 4; ++ni) {
      int srow = ni * 16 + ln;
      const char* kr = (const char*)Ks + srow * 128;
      int x0 = (rg * 16) ^ ((srow & 7) << 4);
      int x1 = (rg * 16 + 64) ^ ((srow & 7) << 4);
      bf16x8 b0 = *(const bf16x8*)(kr + x0);
      bf16x8 b1 = *(const bf16x8*)(kr + x1);
      f32x4 a = __builtin_amdgcn_mfma_f32_16x16x32_bf16(qf0, b0, zero, 0, 0, 0);
      sc4[ni] = __builtin_amdgcn_mfma_f32_16x16x32_bf16(qf1, b1, a, 0, 0, 0);
    }

    float p[4][4], pm[4];
    #pragma unroll
    for (int r = 0; r < 4; ++r) pm[r] = -1e30f;
    #pragma unroll
    for (int ni = 0; ni < 4; ++ni) {
      int sl = ni * 16 + ln;
      #pragma unroll
      for (int r = 0; r < 4; ++r) {
        int dq = qloc_c + r;
        float v = sc4[ni][r] * 0.125f + cfr[r] * tabL[s0 + sl + 63 - dq];
        p[ni][r] = v;
        pm[r] = fmaxf(pm[r], v);
      }
    }
    float scl[4], rs[4];
    #pragma unroll
    for (int r = 0; r < 4; ++r) {
      float v = pm[r];
      v = fmaxf(v, __shfl_xor(v, 1));
      v = fmaxf(v, __shfl_xor(v, 2));
      v = fmaxf(v, __shfl_xor(v, 4));
      v = fmaxf(v, __shfl_xor(v, 8));
      float nm = fmaxf(mrow[r], v);
      scl[r] = expf(mrow[r] - nm);
      mrow[r] = nm;
      rs[r] = 0.f;
    }
    #pragma unroll
    for (int ni = 0; ni < 4; ++ni)
      #pragma unroll
      for (int r = 0; r < 4; ++r) {
        float e = expf(p[ni][r] - mrow[r]);
        p[ni][r] = e;
        rs[r] += e;
      }
    #pragma unroll
    for (int r = 0; r < 4; ++r) {
      float v = rs[r];
      v += __shfl_xor(v, 1);
      v += __shfl_xor(v, 2);
      v += __shfl_xor(v, 4);
      v += __shfl_xor(v, 8);
      lrow[r] = lrow[r] * scl[r] + v;
    }
    #pragma unroll
    for (int ni = 0; ni < 4; ++ni)
      #pragma unroll
      for (int r = 0; r < 4; ++r)
        of[ni][r] *= scl[r];

    #pragma unroll
    for (int ni = 0; ni < 4; ++ni) {
      int sl = ni * 16 + ln;
      #pragma unroll
      for (int r = 0; r < 4; ++r) {
        int row = qloc_c + r;
        int byi = (sl * 2) ^ ((row & 7) << 4);
        *(u16*)((char*)Ps + row * 128 + byi) = f2bf(p[ni][r]);
      }
    }
    bf16x8 pf0, pf1;
    {
      const char* pr = (const char*)Ps + qloc_a * 128;
      int x0 = (rg * 16) ^ ((qloc_a & 7) << 4);
      int x1 = (rg * 16 + 64) ^ ((qloc_a & 7) << 4);
      pf0 = *(const bf16x8*)(pr + x0);
      pf1 = *(const bf16x8*)(pr + x1);
    }
    #pragma unroll
    for (int ni = 0; ni < 4; ++ni) {
      int drow = ni * 16 + ln;
      const char* vr = (const char*)Vts + drow * 128;
      int x0 = (rg * 16) ^ ((drow & 7) << 4);
      int x1 = (rg * 16 + 64) ^ ((drow & 7) << 4);
      bf16x8 v0 = *(const bf16x8*)(vr + x0);
      bf16x8 v1 = *(const bf16x8*)(vr + x1);
      of[ni] = __builtin_amdgcn_mfma_f32_16x16x32_bf16(pf0, v0, of[ni], 0, 0, 0);
      of[ni] = __builtin_amdgcn_mfma_f32_16x16x32_bf16(pf1, v1, of[ni], 0, 0, 0);
    }
    __syncthreads();
  }

  int b = bh >> 3;
  #pragma unroll
  for (int r = 0; r < 4; ++r) {
    float inv = 1.f / lrow[r];
    size_t ro = ((size_t)(b * 1024 + t0 + qloc_c + r)) * 512 + h * 64;
    #pragma unroll
    for (int ni = 0; ni < 4; ++ni)
      o[ro + ni * 16 + ln] = f2bf(of[ni][r] * inv);
  }
}

// ---------------- per-batch 2-moment reduction (atomic) ----------------
__global__ __launch_bounds__(256)
void gn_stats_k(const float* __restrict__ x, float* __restrict__ stats) {
  int b = blockIdx.y;
  const float* xb = x + (size_t)b * (DIM_ * T_);
  float s = 0.f, s2 = 0.f;
  for (int i = blockIdx.x * 256 + threadIdx.x; i < DIM_ * T_; i += 64 * 256) {
    float v = xb[i];
    s += v; s2 += v * v;
  }
  #pragma unroll
  for (int off = 32; off > 0; off >>= 1) {
    s += __shfl_xor(s, off);
    s2 += __shfl_xor(s2, off);
  }
  __shared__ float ps[4], ps2[4];
  int wid = threadIdx.x >> 6;
  if ((threadIdx.x & 63) == 0) { ps[wid] = s; ps2[wid] = s2; }
  __syncthreads();
  if (threadIdx.x == 0) {
    atomicAdd(&stats[b * 2],     ps[0] + ps[1] + ps[2] + ps[3]);
    atomicAdd(&stats[b * 2 + 1], ps2[0] + ps2[1] + ps2[2] + ps2[3]);
  }
}

// ---------------- groupnorm apply (+optional silu), bf16 out ----------------
template<int SILU>
__global__ __launch_bounds__(256)
void gn_apply_k(const float* __restrict__ x, const float* __restrict__ stats,
                const float* __restrict__ g, const float* __restrict__ bt,
                u16* __restrict__ y) {
  int i = blockIdx.x * 256 + threadIdx.x;
  int b = i >> 19;
  int c = i & (DIM_ - 1);
  const float cnt = 1.f / (float)(DIM_ * T_);
  float m = stats[b * 2] * cnt;
  float var = stats[b * 2 + 1] * cnt - m * m;
  float v = (x[i] - m) * rsqrtf(var + 1e-5f) * g[c] + bt[c];
  if (SILU) v = v * sigmoidf_(v);
  y[i] = f2bf(v);
}

// ---------------- GLU: a * sigmoid(g) ----------------
__global__ __launch_bounds__(256)
void glu_k(const float* __restrict__ in, float* __restrict__ out) {
  int i = blockIdx.x * 256 + threadIdx.x;
  int btk = i >> 9, c = i & (DIM_ - 1);
  float a = in[(size_t)btk * 1024 + c];
  float gg = in[(size_t)btk * 1024 + 512 + c];
  out[i] = a * sigmoidf_(gg);
}

// ---------------- depthwise conv: register sliding window ----------------
// thread owns channel c, computes DCT consecutive t outputs from a 46-elem window.
__global__ __launch_bounds__(256)
void dwconv_k(const float* __restrict__ in, const float* __restrict__ w,
              const float* __restrict__ bias, float* __restrict__ out) {
  int c = blockIdx.x * 256 + threadIdx.x;
  int t0 = blockIdx.y * DCT;
  int b = blockIdx.z;
  const float* ib = in + (size_t)b * T_ * DIM_ + c;
  float wr[KW];
  #pragma unroll
  for (int k = 0; k < KW; ++k) wr[k] = w[c * KW + k];
  float win[DCT + KW - 1];
  #pragma unroll
  for (int j = 0; j < DCT + KW - 1; ++j) {
    int tt = t0 + j - 15;
    win[j] = (tt >= 0 && tt < T_) ? ib[(size_t)tt * DIM_] : 0.f;
  }
  float bs = bias[c];
  #pragma unroll
  for (int t = 0; t < DCT; ++t) {
    float acc = bs;
    #pragma unroll
    for (int k = 0; k < KW; ++k)
      acc += win[t + k] * wr[k];
    out[((size_t)b * T_ + t0 + t) * DIM_ + c] = acc;
  }
}

extern "C" void kernel_launch(void* const* d_in, const int* in_sizes, int n_in,
                              void* d_out, int out_size, void* d_ws, size_t ws_size,
                              hipStream_t stream) {
  const float* x      = (const float*)d_in[0];
  const float* ff1_w1 = (const float*)d_in[1];
  const float* ff1_b1 = (const float*)d_in[2];
  const float* ff1_w2 = (const float*)d_in[3];
  const float* ff1_b2 = (const float*)d_in[4];
  const float* qkv_w  = (const float*)d_in[5];
  const float* qkv_b  = (const float*)d_in[6];
  const float* out_w  = (const float*)d_in[7];
  const float* out_b  = (const float*)d_in[8];
  const float* gn1_g  = (const float*)d_in[9];
  const float* gn1_b  = (const float*)d_in[10];
  const float* pw1_w  = (const float*)d_in[11];
  const float* pw1_b  = (const float*)d_in[12];
  const float* dw_w   = (const float*)d_in[13];
  const float* dw_b   = (const float*)d_in[14];
  const float* gn2_g  = (const float*)d_in[15];
  const float* gn2_b  = (const float*)d_in[16];
  const float* pw2_w  = (const float*)d_in[17];
  const float* pw2_b  = (const float*)d_in[18];
  const float* ff2_w1 = (const float*)d_in[19];
  const float* ff2_b1 = (const float*)d_in[20];
  const float* ff2_w2 = (const float*)d_in[21];
  const float* ff2_b2 = (const float*)d_in[22];
  const float* rel_embed = (const float*)d_in[23];
  const float* gate_u = (const float*)d_in[24];
  const float* gate_w = (const float*)d_in[25];
  const float* scale_h = (const float*)d_in[26];
  float* out = (float*)d_out;
  float* ws = (float*)d_ws;

  // fp32 region (float offsets)
  float* S0    = ws;                  // 2M
  float* S1    = ws + 2097152;        // 2M
  float* S2    = ws + 4194304;        // 2M
  float* BIGB  = ws + 6291456;        // 6.3M (qkv out)
  float* STATS = ws + 12582912;       // 16
  float* TAB   = ws + 12582928;       // 16384
  float* CF    = ws + 12599312;       // 32768 -> ends 12632080
  // bf16 region
  u16* B16    = (u16*)(ws + 12632080);
  u16* Ab     = B16;                  // 2M elems
  u16* Ab2    = B16 + 2097152;        // 2M
  u16* FFb    = B16 + 4194304;        // 8.4M
  u16* Qb     = FFb;                  // alias: FFb dead between FFN1 and FFN2
  u16* Kb     = FFb + 2097152;
  u16* Vtb    = FFb + 4194304;
  u16* Wb     = B16 + 12582912;
  u16* ff1w1t = Wb;
  u16* ff1w2t = Wb + 1048576;
  u16* qkvwt  = Wb + 2097152;
  u16* outwt  = Wb + 2883584;
  u16* pw1wb  = Wb + 3145728;
  u16* pw2wb  = Wb + 3670016;
  u16* ff2w1t = Wb + 3932160;
  u16* ff2w2t = Wb + 4980736;         // ends Wb + 6029312

  hipMemsetAsync(STATS, 0, 16 * sizeof(float), stream);

  dim3 tb(32, 8);
  wcvtT_k<<<dim3(FF_ / 32, DIM_ / 32), tb, 0, stream>>>(ff1_w1, ff1w1t, DIM_, FF_);
  wcvtT_k<<<dim3(DIM_ / 32, FF_ / 32), tb, 0, stream>>>(ff1_w2, ff1w2t, FF_, DIM_);
  wcvtT_k<<<dim3(1536 / 32, DIM_ / 32), tb, 0, stream>>>(qkv_w, qkvwt, DIM_, 1536);
  wcvtT_k<<<dim3(DIM_ / 32, DIM_ / 32), tb, 0, stream>>>(out_w, outwt, DIM_, DIM_);
  wcvt_k<<<2048, 256, 0, stream>>>(pw1_w, pw1wb, 524288);
  wcvt_k<<<1024, 256, 0, stream>>>(pw2_w, pw2wb, 262144);
  wcvtT_k<<<dim3(FF_ / 32, DIM_ / 32), tb, 0, stream>>>(ff2_w1, ff2w1t, DIM_, FF_);
  wcvtT_k<<<dim3(DIM_ / 32, FF_ / 32), tb, 0, stream>>>(ff2_w2, ff2w2t, FF_, DIM_);
  table_k<<<64, 256, 0, stream>>>(rel_embed, TAB);

  // x (B,DIM,T) -> S0 fp32 + Ab bf16 (B,T,DIM)
  transpose_cvt_k<<<dim3(T_ / 32, DIM_ / 32, B_), tb, 0, stream>>>(x, S0, Ab, DIM_, T_);
  // FFN1
  bgemm_k<1, 0, 0, 1><<<dim3(16, 32), 256, 0, stream>>>(
      Ab, ff1w1t, ff1_b1, nullptr, 0.f, nullptr, FFb, 4096, FF_, DIM_);
  bgemm_k<0, 1, 1, 1><<<dim3(4, 32), 256, 0, stream>>>(
      FFb, ff1w2t, ff1_b2, S0, 0.5f, S1, Ab, 4096, DIM_, FF_);
  // QKV (fp32 out)
  bgemm_k<0, 0, 1, 0><<<dim3(12, 32), 256, 0, stream>>>(
      Ab, qkvwt, qkv_b, nullptr, 0.f, BIGB, nullptr, 4096, 1536, DIM_);
  // attention prep + MFMA flash attention -> Ab bf16
  qkv_prep_k<<<dim3(32, 16), 256, 0, stream>>>(BIGB, Qb, Kb, Vtb);
  cf_k<<<128, 256, 0, stream>>>(BIGB, gate_u, gate_w, scale_h, CF);
  attn_mfma_k<<<512, 256, 0, stream>>>(Qb, Kb, Vtb, CF, TAB, Ab);
  // out proj + residual (S1 dead afterwards)
  bgemm_k<0, 1, 1, 0><<<dim3(4, 32), 256, 0, stream>>>(
      Ab, outwt, out_b, S1, 1.f, S2, nullptr, 4096, DIM_, DIM_);
  // conv module
  gn_stats_k<<<dim3(64, B_), 256, 0, stream>>>(S2, STATS);
  gn_apply_k<0><<<8192, 256, 0, stream>>>(S2, STATS, gn1_g, gn1_b, Ab);
  bgemm_k<0, 0, 1, 0><<<dim3(8, 32), 256, 0, stream>>>(
      Ab, pw1wb, pw1_b, nullptr, 0.f, BIGB, nullptr, 4096, 1024, DIM_);
  glu_k<<<8192, 256, 0, stream>>>(BIGB, S0);
  dwconv_k<<<dim3(2, T_ / DCT, B_), 256, 0, stream>>>(S0, dw_w, dw_b, S1);
  gn_stats_k<<<dim3(64, B_), 256, 0, stream>>>(S1, STATS + 8);
  gn_apply_k<1><<<8192, 256, 0, stream>>>(S1, STATS + 8, gn2_g, gn2_b, Ab);
  // pw2 + residual -> S1 fp32, Ab2 bf16
  bgemm_k<0, 1, 1, 1><<<dim3(4, 32), 256, 0, stream>>>(
      Ab, pw2wb, pw2_b, S2, 1.f, S1, Ab2, 4096, DIM_, DIM_);
  // FFN2
  bgemm_k<1, 0, 0, 1><<<dim3(16, 32), 256, 0, stream>>>(
      Ab2, ff2w1t, ff2_b1, nullptr, 0.f, nullptr, FFb, 4096, FF_, DIM_);
  bgemm_k<0, 1, 1, 0><<<dim3(4, 32), 256, 0, stream>>>(
      FFb, ff2w2t, ff2_b2, S1, 0.5f, S2, nullptr, 4096, DIM_, FF_);
  transpose_k<<<dim3(DIM_ / 32, T_ / 32, B_), tb, 0, stream>>>(S2, out, T_, DIM_);
}

// Round 12
// 408.828 us; speedup vs baseline: 3.9645x; 1.1869x over previous
//
#include <hip/hip_runtime.h>
#include <math.h>

#define B_ 4
#define T_ 1024
#define DIM_ 512
#define H_ 8
#define DH_ 64
#define FF_ 2048
#define KW 31
#define DCT 16   // dwconv t-outputs per thread

typedef unsigned short u16;
typedef __attribute__((ext_vector_type(8))) short bf16x8;
typedef __attribute__((ext_vector_type(4))) float f32x4;

__device__ __forceinline__ float geluf(float x) {
  return 0.5f * x * (1.f + erff(x * 0.70710678118654752f));
}
__device__ __forceinline__ float sigmoidf_(float x) {
  return 1.f / (1.f + expf(-x));
}
__device__ __forceinline__ u16 f2bf(float f) {
  union { float f; unsigned int u; } v; v.f = f;
  unsigned int u = v.u;
  return (u16)((u + 0x7FFF + ((u >> 16) & 1)) >> 16);  // RNE
}

// ---------------- transpose (B,R,C) -> (B,C,R), fp32 out ----------------
__global__ __launch_bounds__(256)
void transpose_k(const float* __restrict__ in, float* __restrict__ out, int R, int C) {
  __shared__ float tile[32][33];
  int b = blockIdx.z;
  const float* ib = in + (size_t)b * R * C;
  float* ob = out + (size_t)b * R * C;
  int c0 = blockIdx.x * 32, r0 = blockIdx.y * 32;
  int tx = threadIdx.x, ty = threadIdx.y;
  for (int i = ty; i < 32; i += 8)
    tile[i][tx] = ib[(size_t)(r0 + i) * C + c0 + tx];
  __syncthreads();
  for (int i = ty; i < 32; i += 8)
    ob[(size_t)(c0 + i) * R + r0 + tx] = tile[tx][i];
}

// ---------------- transpose + dual write (fp32 + bf16) ----------------
__global__ __launch_bounds__(256)
void transpose_cvt_k(const float* __restrict__ in, float* __restrict__ out,
                     u16* __restrict__ outb, int R, int C) {
  __shared__ float tile[32][33];
  int b = blockIdx.z;
  const float* ib = in + (size_t)b * R * C;
  float* ob = out + (size_t)b * R * C;
  u16* ob2 = outb + (size_t)b * R * C;
  int c0 = blockIdx.x * 32, r0 = blockIdx.y * 32;
  int tx = threadIdx.x, ty = threadIdx.y;
  for (int i = ty; i < 32; i += 8)
    tile[i][tx] = ib[(size_t)(r0 + i) * C + c0 + tx];
  __syncthreads();
  for (int i = ty; i < 32; i += 8) {
    float v = tile[tx][i];
    size_t o = (size_t)(c0 + i) * R + r0 + tx;
    ob[o] = v;
    ob2[o] = f2bf(v);
  }
}

// ---------------- fused weight prep: 8 weight converts + rel-bias table ------
// One dispatch replaces 9. Block ranges (256 threads, 1D):
//  T-convert [K,N]->[N,K] bf16 tiles of 32x32; copies; Toeplitz table.
__device__ __forceinline__ void wcvtT_tile(const float* __restrict__ in,
                                           u16* __restrict__ out, int K, int N,
                                           int blk, int tid, float (*t)[33]) {
  int nb = N / 32;
  int n0 = (blk % nb) * 32, k0 = (blk / nb) * 32;
  int tx = tid & 31, ty = tid >> 5;
  for (int i = ty; i < 32; i += 8)
    t[i][tx] = in[(size_t)(k0 + i) * N + n0 + tx];
  __syncthreads();
  for (int i = ty; i < 32; i += 8)
    out[(size_t)(n0 + i) * K + k0 + tx] = f2bf(t[tx][i]);
}

__global__ __launch_bounds__(256)
void wprep_k(const float* __restrict__ ff1_w1, u16* __restrict__ ff1w1t,
             const float* __restrict__ ff1_w2, u16* __restrict__ ff1w2t,
             const float* __restrict__ qkv_w,  u16* __restrict__ qkvwt,
             const float* __restrict__ out_w,  u16* __restrict__ outwt,
             const float* __restrict__ pw1_w,  u16* __restrict__ pw1wb,
             const float* __restrict__ pw2_w,  u16* __restrict__ pw2wb,
             const float* __restrict__ ff2_w1, u16* __restrict__ ff2w1t,
             const float* __restrict__ ff2_w2, u16* __restrict__ ff2w2t,
             const float* __restrict__ rel_embed, float* __restrict__ table) {
  __shared__ float t[32][33];
  int blk = blockIdx.x;
  int tid = threadIdx.x;
  // ranges: 1024,1024,768,256,1024,1024 (T) ; 256,128 (copy) ; 64 (table)
  if (blk < 1024) { wcvtT_tile(ff1_w1, ff1w1t, 512, 2048, blk, tid, t); return; }
  blk -= 1024;
  if (blk < 1024) { wcvtT_tile(ff1_w2, ff1w2t, 2048, 512, blk, tid, t); return; }
  blk -= 1024;
  if (blk < 768)  { wcvtT_tile(qkv_w, qkvwt, 512, 1536, blk, tid, t); return; }
  blk -= 768;
  if (blk < 256)  { wcvtT_tile(out_w, outwt, 512, 512, blk, tid, t); return; }
  blk -= 256;
  if (blk < 1024) { wcvtT_tile(ff2_w1, ff2w1t, 512, 2048, blk, tid, t); return; }
  blk -= 1024;
  if (blk < 1024) { wcvtT_tile(ff2_w2, ff2w2t, 2048, 512, blk, tid, t); return; }
  blk -= 1024;
  if (blk < 256) {  // pw1 copy: 524288 elems, 2048/block
    size_t base = (size_t)blk * 2048 + tid * 8;
    #pragma unroll
    for (int j = 0; j < 8; ++j) pw1wb[base + j] = f2bf(pw1_w[base + j]);
    return;
  }
  blk -= 256;
  if (blk < 128) {  // pw2 copy: 262144 elems
    size_t base = (size_t)blk * 2048 + tid * 8;
    #pragma unroll
    for (int j = 0; j < 8; ++j) pw2wb[base + j] = f2bf(pw2_w[base + j]);
    return;
  }
  blk -= 128;
  {  // table: 8*2047 elems
    int idx = blk * 256 + tid;
    if (idx >= H_ * 2047) return;
    int h = idx / 2047, j = idx % 2047;
    int rel = j - 1023;
    int sign = rel >= 0 ? 1 : 0;
    int ap = rel >= 0 ? rel : -rel;
    int val;
    if (ap < 80) {
      val = ap;
    } else {
      float lr = logf((float)(ap > 1 ? ap : 1) / 80.f) / logf(10.f);
      int lp = (int)(80.f + lr * 80.f);
      val = lp < 159 ? lp : 159;
    }
    int bucket = val + sign * 160;
    bucket = bucket < 0 ? 0 : (bucket > 319 ? 319 : bucket);
    table[h * 2047 + j] = rel_embed[bucket * H_ + h];
  }
}

// ---------------- bf16 MFMA GEMM 128x128x32 (verified Round 5) ----------------
template<int ACT, int HASRES, int WF32, int WB16>
__global__ __launch_bounds__(256)
void bgemm_k(const u16* __restrict__ A, const u16* __restrict__ Bt,
             const float* __restrict__ bias, const float* __restrict__ res,
             float resScale, float* __restrict__ Cf, u16* __restrict__ Cb,
             int M, int N, int K) {
  __shared__ u16 As[128 * 32];
  __shared__ u16 Bs[128 * 32];
  int tid = threadIdx.x;
  int wave = tid >> 6, lane = tid & 63;
  int bm = blockIdx.y * 128, bn = blockIdx.x * 128;
  int wm = (wave >> 1) * 64, wn = (wave & 1) * 64;
  f32x4 acc[4][4];
  f32x4 zero = {0.f, 0.f, 0.f, 0.f};
  #pragma unroll
  for (int i = 0; i < 4; ++i)
    #pragma unroll
    for (int j = 0; j < 4; ++j) acc[i][j] = zero;

  int srow = tid >> 2;
  int skc = (tid & 3) * 8;
  const u16* Ag = A + (size_t)(bm + srow) * K + skc;
  const u16* Bg = Bt + (size_t)(bn + srow) * K + skc;
  char* AsW = (char*)As + wave * 1024;
  char* BsW = (char*)Bs + wave * 1024;
  int fr = lane & 15, fk = (lane >> 4) * 8;

  for (int kt = 0; kt < K; kt += 32) {
    __builtin_amdgcn_global_load_lds(
        (const __attribute__((address_space(1))) void*)(Ag + kt),
        (__attribute__((address_space(3))) void*)AsW, 16, 0, 0);
    __builtin_amdgcn_global_load_lds(
        (const __attribute__((address_space(1))) void*)(Ag + kt + (size_t)64 * K),
        (__attribute__((address_space(3))) void*)(AsW + 4096), 16, 0, 0);
    __builtin_amdgcn_global_load_lds(
        (const __attribute__((address_space(1))) void*)(Bg + kt),
        (__attribute__((address_space(3))) void*)BsW, 16, 0, 0);
    __builtin_amdgcn_global_load_lds(
        (const __attribute__((address_space(1))) void*)(Bg + kt + (size_t)64 * K),
        (__attribute__((address_space(3))) void*)(BsW + 4096), 16, 0, 0);
    __syncthreads();
    bf16x8 af[4], bf[4];
    #pragma unroll
    for (int mi = 0; mi < 4; ++mi)
      af[mi] = *(const bf16x8*)(As + (wm + mi * 16 + fr) * 32 + fk);
    #pragma unroll
    for (int ni = 0; ni < 4; ++ni)
      bf[ni] = *(const bf16x8*)(Bs + (wn + ni * 16 + fr) * 32 + fk);
    #pragma unroll
    for (int mi = 0; mi < 4; ++mi)
      #pragma unroll
      for (int ni = 0; ni < 4; ++ni)
        acc[mi][ni] = __builtin_amdgcn_mfma_f32_16x16x32_bf16(
            af[mi], bf[ni], acc[mi][ni], 0, 0, 0);
    __syncthreads();
  }
  int cr4 = (lane >> 4) * 4;
  int cc = lane & 15;
  #pragma unroll
  for (int mi = 0; mi < 4; ++mi) {
    #pragma unroll
    for (int r = 0; r < 4; ++r) {
      int row = bm + wm + mi * 16 + cr4 + r;
      size_t ro = (size_t)row * N;
      #pragma unroll
      for (int ni = 0; ni < 4; ++ni) {
        int c = bn + wn + ni * 16 + cc;
        float v = acc[mi][ni][r] + bias[c];
        if (ACT) v = geluf(v);
        if (HASRES) v = res[ro + c] + resScale * v;
        if (WF32) Cf[ro + c] = v;
        if (WB16) Cb[ro + c] = f2bf(v);
      }
    }
  }
}

// ---------------- bf16 MFMA GEMM 64x64x32 (small-N: 4x the blocks) ----------
// Same staging idiom / fragment math as bgemm_k; wave tile 32x32 (2x2 frags).
template<int ACT, int HASRES, int WF32, int WB16>
__global__ __launch_bounds__(256)
void bgemm64_k(const u16* __restrict__ A, const u16* __restrict__ Bt,
               const float* __restrict__ bias, const float* __restrict__ res,
               float resScale, float* __restrict__ Cf, u16* __restrict__ Cb,
               int M, int N, int K) {
  __shared__ u16 As[64 * 32];
  __shared__ u16 Bs[64 * 32];
  int tid = threadIdx.x;
  int wave = tid >> 6, lane = tid & 63;
  int bm = blockIdx.y * 64, bn = blockIdx.x * 64;
  int wm = (wave >> 1) * 32, wn = (wave & 1) * 32;
  f32x4 acc[2][2];
  f32x4 zero = {0.f, 0.f, 0.f, 0.f};
  #pragma unroll
  for (int i = 0; i < 2; ++i)
    #pragma unroll
    for (int j = 0; j < 2; ++j) acc[i][j] = zero;

  int srow = tid >> 2;          // 0..63 rows, 4 k-chunks each
  int skc = (tid & 3) * 8;
  const u16* Ag = A + (size_t)(bm + srow) * K + skc;
  const u16* Bg = Bt + (size_t)(bn + srow) * K + skc;
  char* AsW = (char*)As + wave * 1024;  // chunk tid -> byte tid*16
  char* BsW = (char*)Bs + wave * 1024;
  int fr = lane & 15, fk = (lane >> 4) * 8;

  for (int kt = 0; kt < K; kt += 32) {
    __builtin_amdgcn_global_load_lds(
        (const __attribute__((address_space(1))) void*)(Ag + kt),
        (__attribute__((address_space(3))) void*)AsW, 16, 0, 0);
    __builtin_amdgcn_global_load_lds(
        (const __attribute__((address_space(1))) void*)(Bg + kt),
        (__attribute__((address_space(3))) void*)BsW, 16, 0, 0);
    __syncthreads();
    bf16x8 af[2], bf[2];
    #pragma unroll
    for (int mi = 0; mi < 2; ++mi)
      af[mi] = *(const bf16x8*)(As + (wm + mi * 16 + fr) * 32 + fk);
    #pragma unroll
    for (int ni = 0; ni < 2; ++ni)
      bf[ni] = *(const bf16x8*)(Bs + (wn + ni * 16 + fr) * 32 + fk);
    #pragma unroll
    for (int mi = 0; mi < 2; ++mi)
      #pragma unroll
      for (int ni = 0; ni < 2; ++ni)
        acc[mi][ni] = __builtin_amdgcn_mfma_f32_16x16x32_bf16(
            af[mi], bf[ni], acc[mi][ni], 0, 0, 0);
    __syncthreads();
  }
  int cr4 = (lane >> 4) * 4;
  int cc = lane & 15;
  #pragma unroll
  for (int mi = 0; mi < 2; ++mi) {
    #pragma unroll
    for (int r = 0; r < 4; ++r) {
      int row = bm + wm + mi * 16 + cr4 + r;
      size_t ro = (size_t)row * N;
      #pragma unroll
      for (int ni = 0; ni < 2; ++ni) {
        int c = bn + wn + ni * 16 + cc;
        float v = acc[mi][ni][r] + bias[c];
        if (ACT) v = geluf(v);
        if (HASRES) v = res[ro + c] + resScale * v;
        if (WF32) Cf[ro + c] = v;
        if (WB16) Cb[ro + c] = f2bf(v);
      }
    }
  }
}

// ---------------- QKV prep (coalesced): block = (bh, 64-t tile) ----------------
__global__ __launch_bounds__(256)
void qkv_prep_k(const float* __restrict__ qkv, u16* __restrict__ Qb,
                u16* __restrict__ Kb, u16* __restrict__ Vtb) {
  __shared__ float vt[64][65];
  int bh = blockIdx.x;
  int h = bh & 7, b = bh >> 3;
  int t0 = blockIdx.y * 64;
  int tid = threadIdx.x;
  int d = tid & 63, tr = tid >> 6;
  #pragma unroll
  for (int i = 0; i < 16; ++i) {
    int t = i * 4 + tr;
    const float* src = qkv + ((size_t)(b * 1024 + t0 + t)) * 1536 + h * 64 + d;
    size_t o = (size_t)bh * 65536 + (t0 + t) * 64 + d;
    Qb[o] = f2bf(src[0]);
    Kb[o] = f2bf(src[512]);
    vt[t][d] = src[1024];
  }
  __syncthreads();
  int tl = tid & 63, dr = tid >> 6;
  #pragma unroll
  for (int i = 0; i < 16; ++i) {
    int dd = i * 4 + dr;
    Vtb[((size_t)bh * 64 + dd) * 1024 + t0 + tl] = f2bf(vt[tl][dd]);
  }
}

// ---------------- gate coefficients: CF[bh*1024+t] ----------------
__global__ __launch_bounds__(256)
void cf_k(const float* __restrict__ qkv, const float* __restrict__ gate_u,
          const float* __restrict__ gate_w, const float* __restrict__ scale_h,
          float* __restrict__ CF) {
  int j = blockIdx.x * 256 + threadIdx.x;  // 32768
  int bh = j >> 10, t = j & 1023;
  int h = bh & 7, b = bh >> 3;
  const float* q = qkv + ((size_t)(b * 1024 + t)) * 1536 + h * 64;
  float gu = 0.f, gw = 0.f;
  #pragma unroll
  for (int d4 = 0; d4 < 16; ++d4) {
    float4 qv = *(const float4*)(q + d4 * 4);
    float4 uv = *(const float4*)(gate_u + h * 64 + d4 * 4);
    float4 wv = *(const float4*)(gate_w + h * 64 + d4 * 4);
    gu += qv.x * uv.x + qv.y * uv.y + qv.z * uv.z + qv.w * uv.w;
    gw += qv.x * wv.x + qv.y * wv.y + qv.z * wv.z + qv.w * wv.w;
  }
  gu = sigmoidf_(gu);
  gw = sigmoidf_(gw);
  CF[j] = 1.f + gu + (1.f - gu) * scale_h[h] * gw;
}

// ---------------- MFMA flash attention (verified Round 6) ----------------
__global__ __launch_bounds__(256)
void attn_mfma_k(const u16* __restrict__ Qb, const u16* __restrict__ Kb,
                 const u16* __restrict__ Vtb, const float* __restrict__ CF,
                 const float* __restrict__ table, u16* __restrict__ o) {
  __shared__ u16 Ks[4096];
  __shared__ u16 Vts[4096];
  __shared__ u16 Ps[4096];
  __shared__ float tabL[1104];
  int blk = blockIdx.x;
  int qt = blk & 15;
  int bh = blk >> 4;
  int h = bh & 7;
  int t0 = qt * 64;
  int tid = threadIdx.x;
  int wave = tid >> 6, lane = tid & 63;
  int w16 = wave * 16;
  int rg = lane >> 4;
  int ln = lane & 15;
  int qloc_a = w16 + ln;
  int qloc_c = w16 + rg * 4;

  for (int i = tid; i < 1087; i += 256)
    tabL[i] = table[h * 2047 + 960 - t0 + i];

  bf16x8 qf0, qf1;
  {
    const u16* Qg = Qb + ((size_t)bh * 1024 + t0 + qloc_a) * 64 + rg * 8;
    qf0 = *(const bf16x8*)(Qg);
    qf1 = *(const bf16x8*)(Qg + 32);
  }
  float cfr[4];
  #pragma unroll
  for (int r = 0; r < 4; ++r)
    cfr[r] = CF[(size_t)bh * 1024 + t0 + qloc_c + r];

  float mrow[4] = {-1e30f, -1e30f, -1e30f, -1e30f};
  float lrow[4] = {0.f, 0.f, 0.f, 0.f};
  f32x4 of[4];
  f32x4 zero = {0.f, 0.f, 0.f, 0.f};
  #pragma unroll
  for (int ni = 0; ni < 4; ++ni) of[ni] = zero;

  int srow0 = tid >> 3, sch = tid & 7;
  char* KsW = (char*)Ks + wave * 1024;
  char* VtsW = (char*)Vts + wave * 1024;

  for (int kt = 0; kt < 16; ++kt) {
    int s0 = kt * 64;
    #pragma unroll
    for (int c = 0; c < 2; ++c) {
      int row = srow0 + c * 32;
      const u16* ksrc = Kb + ((size_t)bh * 1024 + s0 + row) * 64 + ((sch ^ (row & 7)) * 8);
      const u16* vsrc = Vtb + ((size_t)bh * 64 + row) * 1024 + s0 + ((sch ^ (row & 7)) * 8);
      __builtin_amdgcn_global_load_lds(
          (const __attribute__((address_space(1))) void*)ksrc,
          (__attribute__((address_space(3))) void*)(KsW + c * 4096), 16, 0, 0);
      __builtin_amdgcn_global_load_lds(
          (const __attribute__((address_space(1))) void*)vsrc,
          (__attribute__((address_space(3))) void*)(VtsW + c * 4096), 16, 0, 0);
    }
    __syncthreads();

    f32x4 sc4[4];
    #pragma unroll
    for (int ni = 0; ni < 4; ++ni) {
      int srow = ni * 16 + ln;
      const char* kr = (const char*)Ks + srow * 128;
      int x0 = (rg * 16) ^ ((srow & 7) << 4);
      int x1 = (rg * 16 + 64) ^ ((srow & 7) << 4);
      bf16x8 b0 = *(const bf16x8*)(kr + x0);
      bf16x8 b1 = *(const bf16x8*)(kr + x1);
      f32x4 a = __builtin_amdgcn_mfma_f32_16x16x32_bf16(qf0, b0, zero, 0, 0, 0);
      sc4[ni] = __builtin_amdgcn_mfma_f32_16x16x32_bf16(qf1, b1, a, 0, 0, 0);
    }

    float p[4][4], pm[4];
    #pragma unroll
    for (int r = 0; r < 4; ++r) pm[r] = -1e30f;
    #pragma unroll
    for (int ni = 0; ni < 4; ++ni) {
      int sl = ni * 16 + ln;
      #pragma unroll
      for (int r = 0; r < 4; ++r) {
        int dq = qloc_c + r;
        float v = sc4[ni][r] * 0.125f + cfr[r] * tabL[s0 + sl + 63 - dq];
        p[ni][r] = v;
        pm[r] = fmaxf(pm[r], v);
      }
    }
    float scl[4], rs[4];
    #pragma unroll
    for (int r = 0; r < 4; ++r) {
      float v = pm[r];
      v = fmaxf(v, __shfl_xor(v, 1));
      v = fmaxf(v, __shfl_xor(v, 2));
      v = fmaxf(v, __shfl_xor(v, 4));
      v = fmaxf(v, __shfl_xor(v, 8));
      float nm = fmaxf(mrow[r], v);
      scl[r] = expf(mrow[r] - nm);
      mrow[r] = nm;
      rs[r] = 0.f;
    }
    #pragma unroll
    for (int ni = 0; ni < 4; ++ni)
      #pragma unroll
      for (int r = 0; r < 4; ++r) {
        float e = expf(p[ni][r] - mrow[r]);
        p[ni][r] = e;
        rs[r] += e;
      }
    #pragma unroll
    for (int r = 0; r < 4; ++r) {
      float v = rs[r];
      v += __shfl_xor(v, 1);
      v += __shfl_xor(v, 2);
      v += __shfl_xor(v, 4);
      v += __shfl_xor(v, 8);
      lrow[r] = lrow[r] * scl[r] + v;
    }
    #pragma unroll
    for (int ni = 0; ni < 4; ++ni)
      #pragma unroll
      for (int r = 0; r < 4; ++r)
        of[ni][r] *= scl[r];

    #pragma unroll
    for (int ni = 0; ni < 4; ++ni) {
      int sl = ni * 16 + ln;
      #pragma unroll
      for (int r = 0; r < 4; ++r) {
        int row = qloc_c + r;
        int byi = (sl * 2) ^ ((row & 7) << 4);
        *(u16*)((char*)Ps + row * 128 + byi) = f2bf(p[ni][r]);
      }
    }
    bf16x8 pf0, pf1;
    {
      const char* pr = (const char*)Ps + qloc_a * 128;
      int x0 = (rg * 16) ^ ((qloc_a & 7) << 4);
      int x1 = (rg * 16 + 64) ^ ((qloc_a & 7) << 4);
      pf0 = *(const bf16x8*)(pr + x0);
      pf1 = *(const bf16x8*)(pr + x1);
    }
    #pragma unroll
    for (int ni = 0; ni < 4; ++ni) {
      int drow = ni * 16 + ln;
      const char* vr = (const char*)Vts + drow * 128;
      int x0 = (rg * 16) ^ ((drow & 7) << 4);
      int x1 = (rg * 16 + 64) ^ ((drow & 7) << 4);
      bf16x8 v0 = *(const bf16x8*)(vr + x0);
      bf16x8 v1 = *(const bf16x8*)(vr + x1);
      of[ni] = __builtin_amdgcn_mfma_f32_16x16x32_bf16(pf0, v0, of[ni], 0, 0, 0);
      of[ni] = __builtin_amdgcn_mfma_f32_16x16x32_bf16(pf1, v1, of[ni], 0, 0, 0);
    }
    __syncthreads();
  }

  int b = bh >> 3;
  #pragma unroll
  for (int r = 0; r < 4; ++r) {
    float inv = 1.f / lrow[r];
    size_t ro = ((size_t)(b * 1024 + t0 + qloc_c + r)) * 512 + h * 64;
    #pragma unroll
    for (int ni = 0; ni < 4; ++ni)
      o[ro + ni * 16 + ln] = f2bf(of[ni][r] * inv);
  }
}

// ---------------- per-batch 2-moment reduction (atomic) ----------------
__global__ __launch_bounds__(256)
void gn_stats_k(const float* __restrict__ x, float* __restrict__ stats) {
  int b = blockIdx.y;
  const float* xb = x + (size_t)b * (DIM_ * T_);
  float s = 0.f, s2 = 0.f;
  for (int i = blockIdx.x * 256 + threadIdx.x; i < DIM_ * T_; i += 64 * 256) {
    float v = xb[i];
    s += v; s2 += v * v;
  }
  #pragma unroll
  for (int off = 32; off > 0; off >>= 1) {
    s += __shfl_xor(s, off);
    s2 += __shfl_xor(s2, off);
  }
  __shared__ float ps[4], ps2[4];
  int wid = threadIdx.x >> 6;
  if ((threadIdx.x & 63) == 0) { ps[wid] = s; ps2[wid] = s2; }
  __syncthreads();
  if (threadIdx.x == 0) {
    atomicAdd(&stats[b * 2],     ps[0] + ps[1] + ps[2] + ps[3]);
    atomicAdd(&stats[b * 2 + 1], ps2[0] + ps2[1] + ps2[2] + ps2[3]);
  }
}

// ---------------- groupnorm apply (+optional silu), bf16 out ----------------
template<int SILU>
__global__ __launch_bounds__(256)
void gn_apply_k(const float* __restrict__ x, const float* __restrict__ stats,
                const float* __restrict__ g, const float* __restrict__ bt,
                u16* __restrict__ y) {
  int i = blockIdx.x * 256 + threadIdx.x;
  int b = i >> 19;
  int c = i & (DIM_ - 1);
  const float cnt = 1.f / (float)(DIM_ * T_);
  float m = stats[b * 2] * cnt;
  float var = stats[b * 2 + 1] * cnt - m * m;
  float v = (x[i] - m) * rsqrtf(var + 1e-5f) * g[c] + bt[c];
  if (SILU) v = v * sigmoidf_(v);
  y[i] = f2bf(v);
}

// ---------------- GLU: a * sigmoid(g) ----------------
__global__ __launch_bounds__(256)
void glu_k(const float* __restrict__ in, float* __restrict__ out) {
  int i = blockIdx.x * 256 + threadIdx.x;
  int btk = i >> 9, c = i & (DIM_ - 1);
  float a = in[(size_t)btk * 1024 + c];
  float gg = in[(size_t)btk * 1024 + 512 + c];
  out[i] = a * sigmoidf_(gg);
}

// ---------------- depthwise conv: register sliding window ----------------
__global__ __launch_bounds__(256)
void dwconv_k(const float* __restrict__ in, const float* __restrict__ w,
              const float* __restrict__ bias, float* __restrict__ out) {
  int c = blockIdx.x * 256 + threadIdx.x;
  int t0 = blockIdx.y * DCT;
  int b = blockIdx.z;
  const float* ib = in + (size_t)b * T_ * DIM_ + c;
  float wr[KW];
  #pragma unroll
  for (int k = 0; k < KW; ++k) wr[k] = w[c * KW + k];
  float win[DCT + KW - 1];
  #pragma unroll
  for (int j = 0; j < DCT + KW - 1; ++j) {
    int tt = t0 + j - 15;
    win[j] = (tt >= 0 && tt < T_) ? ib[(size_t)tt * DIM_] : 0.f;
  }
  float bs = bias[c];
  #pragma unroll
  for (int t = 0; t < DCT; ++t) {
    float acc = bs;
    #pragma unroll
    for (int k = 0; k < KW; ++k)
      acc += win[t + k] * wr[k];
    out[((size_t)b * T_ + t0 + t) * DIM_ + c] = acc;
  }
}

extern "C" void kernel_launch(void* const* d_in, const int* in_sizes, int n_in,
                              void* d_out, int out_size, void* d_ws, size_t ws_size,
                              hipStream_t stream) {
  const float* x      = (const float*)d_in[0];
  const float* ff1_w1 = (const float*)d_in[1];
  const float* ff1_b1 = (const float*)d_in[2];
  const float* ff1_w2 = (const float*)d_in[3];
  const float* ff1_b2 = (const float*)d_in[4];
  const float* qkv_w  = (const float*)d_in[5];
  const float* qkv_b  = (const float*)d_in[6];
  const float* out_w  = (const float*)d_in[7];
  const float* out_b  = (const float*)d_in[8];
  const float* gn1_g  = (const float*)d_in[9];
  const float* gn1_b  = (const float*)d_in[10];
  const float* pw1_w  = (const float*)d_in[11];
  const float* pw1_b  = (const float*)d_in[12];
  const float* dw_w   = (const float*)d_in[13];
  const float* dw_b   = (const float*)d_in[14];
  const float* gn2_g  = (const float*)d_in[15];
  const float* gn2_b  = (const float*)d_in[16];
  const float* pw2_w  = (const float*)d_in[17];
  const float* pw2_b  = (const float*)d_in[18];
  const float* ff2_w1 = (const float*)d_in[19];
  const float* ff2_b1 = (const float*)d_in[20];
  const float* ff2_w2 = (const float*)d_in[21];
  const float* ff2_b2 = (const float*)d_in[22];
  const float* rel_embed = (const float*)d_in[23];
  const float* gate_u = (const float*)d_in[24];
  const float* gate_w = (const float*)d_in[25];
  const float* scale_h = (const float*)d_in[26];
  float* out = (float*)d_out;
  float* ws = (float*)d_ws;

  // fp32 region (float offsets)
  float* S0    = ws;                  // 2M
  float* S1    = ws + 2097152;        // 2M
  float* S2    = ws + 4194304;        // 2M
  float* BIGB  = ws + 6291456;        // 6.3M (qkv out)
  float* STATS = ws + 12582912;       // 16
  float* TAB   = ws + 12582928;       // 16384
  float* CF    = ws + 12599312;       // 32768 -> ends 12632080
  // bf16 region
  u16* B16    = (u16*)(ws + 12632080);
  u16* Ab     = B16;                  // 2M elems
  u16* Ab2    = B16 + 2097152;        // 2M
  u16* FFb    = B16 + 4194304;        // 8.4M
  u16* Qb     = FFb;                  // alias: FFb dead between FFN1 and FFN2
  u16* Kb     = FFb + 2097152;
  u16* Vtb    = FFb + 4194304;
  u16* Wb     = B16 + 12582912;
  u16* ff1w1t = Wb;
  u16* ff1w2t = Wb + 1048576;
  u16* qkvwt  = Wb + 2097152;
  u16* outwt  = Wb + 2883584;
  u16* pw1wb  = Wb + 3145728;
  u16* pw2wb  = Wb + 3670016;
  u16* ff2w1t = Wb + 3932160;
  u16* ff2w2t = Wb + 4980736;         // ends Wb + 6029312

  hipMemsetAsync(STATS, 0, 16 * sizeof(float), stream);

  dim3 tb(32, 8);
  // fused weight prep: 6 transposes (1024+1024+768+256+1024+1024) + 2 copies
  // (256+128) + table (64) = 5568 blocks
  wprep_k<<<5568, 256, 0, stream>>>(
      ff1_w1, ff1w1t, ff1_w2, ff1w2t, qkv_w, qkvwt, out_w, outwt,
      pw1_w, pw1wb, pw2_w, pw2wb, ff2_w1, ff2w1t, ff2_w2, ff2w2t,
      rel_embed, TAB);

  // x (B,DIM,T) -> S0 fp32 + Ab bf16 (B,T,DIM)
  transpose_cvt_k<<<dim3(T_ / 32, DIM_ / 32, B_), tb, 0, stream>>>(x, S0, Ab, DIM_, T_);
  // FFN1
  bgemm_k<1, 0, 0, 1><<<dim3(16, 32), 256, 0, stream>>>(
      Ab, ff1w1t, ff1_b1, nullptr, 0.f, nullptr, FFb, 4096, FF_, DIM_);
  bgemm64_k<0, 1, 1, 1><<<dim3(8, 64), 256, 0, stream>>>(
      FFb, ff1w2t, ff1_b2, S0, 0.5f, S1, Ab, 4096, DIM_, FF_);
  // QKV (fp32 out)
  bgemm_k<0, 0, 1, 0><<<dim3(12, 32), 256, 0, stream>>>(
      Ab, qkvwt, qkv_b, nullptr, 0.f, BIGB, nullptr, 4096, 1536, DIM_);
  // attention prep + MFMA flash attention -> Ab bf16
  qkv_prep_k<<<dim3(32, 16), 256, 0, stream>>>(BIGB, Qb, Kb, Vtb);
  cf_k<<<128, 256, 0, stream>>>(BIGB, gate_u, gate_w, scale_h, CF);
  attn_mfma_k<<<512, 256, 0, stream>>>(Qb, Kb, Vtb, CF, TAB, Ab);
  // out proj + residual (S1 dead afterwards)
  bgemm64_k<0, 1, 1, 0><<<dim3(8, 64), 256, 0, stream>>>(
      Ab, outwt, out_b, S1, 1.f, S2, nullptr, 4096, DIM_, DIM_);
  // conv module
  gn_stats_k<<<dim3(64, B_), 256, 0, stream>>>(S2, STATS);
  gn_apply_k<0><<<8192, 256, 0, stream>>>(S2, STATS, gn1_g, gn1_b, Ab);
  bgemm64_k<0, 0, 1, 0><<<dim3(16, 64), 256, 0, stream>>>(
      Ab, pw1wb, pw1_b, nullptr, 0.f, BIGB, nullptr, 4096, 1024, DIM_);
  glu_k<<<8192, 256, 0, stream>>>(BIGB, S0);
  dwconv_k<<<dim3(2, T_ / DCT, B_), 256, 0, stream>>>(S0, dw_w, dw_b, S1);
  gn_stats_k<<<dim3(64, B_), 256, 0, stream>>>(S1, STATS + 8);
  gn_apply_k<1><<<8192, 256, 0, stream>>>(S1, STATS + 8, gn2_g, gn2_b, Ab);
  // pw2 + residual -> S1 fp32, Ab2 bf16
  bgemm64_k<0, 1, 1, 1><<<dim3(8, 64), 256, 0, stream>>>(
      Ab, pw2wb, pw2_b, S2, 1.f, S1, Ab2, 4096, DIM_, DIM_);
  // FFN2
  bgemm_k<1, 0, 0, 1><<<dim3(16, 32), 256, 0, stream>>>(
      Ab2, ff2w1t, ff2_b1, nullptr, 0.f, nullptr, FFb, 4096, FF_, DIM_);
  bgemm64_k<0, 1, 1, 0><<<dim3(8, 64), 256, 0, stream>>>(
      FFb, ff2w2t, ff2_b2, S1, 0.5f, S2, nullptr, 4096, DIM_, FF_);
  transpose_k<<<dim3(DIM_ / 32, T_ / 32, B_), tb, 0, stream>>>(S2, out, T_, DIM_);
}